// Round 17
// baseline (503.247 us; speedup 1.0000x reference)
//
#include <hip/hip_runtime.h>

namespace {
constexpr int B = 2;
constexpr int N = 2048;
constexpr int QD = 1152;
constexpr int H = 16;
constexpr int D = 72;
constexpr int INNER = 1152;
constexpr int NKEEP = 819;            // int(2048*0.4)
constexpr int PSL = 32;               // power-iteration i-slices (matvec out)
constexpr int ILEN = N / PSL;         // 64
constexpr int DP = 80;                // padded head dim (5 blocks of 16)
constexpr int LSTR = 88;              // LDS row stride (bf16) for DP-wide tiles
constexpr int ASL = 16;               // argmax row-slices
constexpr int ACH = (NKEEP + ASL - 1) / ASL;  // 52
constexpr int ROWS = B * H * N;       // 65536
constexpr int X4 = (B * N * QD) / 4;  // 1179648 float4 units of x
}

#define FINF __builtin_inff()
#define SCALE 0.11785113019775793f

typedef __attribute__((ext_vector_type(8))) __bf16 bf16x8;
typedef __attribute__((ext_vector_type(16))) float f32x16;
typedef __attribute__((ext_vector_type(8))) short short8;
typedef __attribute__((ext_vector_type(4))) short short4v;

__device__ __forceinline__ f32x16 mfma_bf16(bf16x8 a, bf16x8 b, f32x16 c) {
  return __builtin_amdgcn_mfma_f32_32x32x16_bf16(a, b, c, 0, 0, 0);
}
__device__ __forceinline__ short f2bf(float x) {
  unsigned u = __float_as_uint(x);
  unsigned r = (u + 0x7fffu + ((u >> 16) & 1u)) >> 16;
  return (short)r;
}
__device__ __forceinline__ float bf2f(short b) {
  return __uint_as_float(((unsigned)(unsigned short)b) << 16);
}

// ------- prep: vectorized x hi/lo split (float4) + QKV pad-column zeroing
__global__ __launch_bounds__(256) void k_prep(
    const float* __restrict__ X, short* __restrict__ Xh, short* __restrict__ Xl,
    short* __restrict__ qkv)
{
  int g = blockIdx.x * 256 + threadIdx.x;   // grid = X4 + 6*ROWS threads exactly
  if (g < X4) {
    float4 v = ((const float4*)X)[g];
    float vv[4] = {v.x, v.y, v.z, v.w};
    short4v h, l;
#pragma unroll
    for (int i = 0; i < 4; ++i) {
      short hb = f2bf(vv[i]);
      h[i] = hb;
      l[i] = f2bf(vv[i] - bf2f(hb));
    }
    *(short4v*)(void*)(Xh + (size_t)g * 4) = h;
    *(short4v*)(void*)(Xl + (size_t)g * 4) = l;
  } else {
    int t = g - X4;                         // 0 .. 6*ROWS-1
    int arr = t / ROWS, row = t - arr * ROWS;
    *(float4*)(void*)(qkv + (size_t)arr * ROWS * DP + (size_t)row * DP + 72) =
        make_float4(0.f, 0.f, 0.f, 0.f);
  }
}

// ---- W (KxN) -> WT hi/lo (N-major, split); z 0..2 -> Wq/Wk/Wv, z=3 -> Wo
__global__ __launch_bounds__(256) void k_wsplit4(
    const float* __restrict__ W0, const float* __restrict__ W1,
    const float* __restrict__ W2, const float* __restrict__ W3,
    short* __restrict__ WTh, short* __restrict__ WTl,
    short* __restrict__ WoTh, short* __restrict__ WoTl)
{
  __shared__ float tile[64][65];
  const int tid = threadIdx.x;
  const int k0 = blockIdx.y * 64, n0 = blockIdx.x * 64;
  const int z = blockIdx.z;
  const float* W = (z == 0) ? W0 : (z == 1) ? W1 : (z == 2) ? W2 : W3;
  short* outH = (z < 3) ? WTh + (size_t)z * QD * INNER : WoTh;
  short* outL = (z < 3) ? WTl + (size_t)z * QD * INNER : WoTl;
  {
    int r = tid >> 2, c0 = (tid & 3) * 16;
#pragma unroll
    for (int j = 0; j < 16; j += 4) {
      float4 v = *(const float4*)&W[(size_t)(k0 + r) * 1152 + n0 + c0 + j];
      tile[r][c0 + j] = v.x; tile[r][c0 + j + 1] = v.y;
      tile[r][c0 + j + 2] = v.z; tile[r][c0 + j + 3] = v.w;
    }
  }
  __syncthreads();
  for (int e = tid; e < 4096; e += 256) {
    int nr = e >> 6, kc = e & 63;
    float v = tile[kc][nr];
    short hb = f2bf(v);
    outH[(size_t)(n0 + nr) * 1152 + k0 + kc] = hb;
    outL[(size_t)(n0 + nr) * 1152 + k0 + kc] = f2bf(v - bf2f(hb));
  }
}

// ------------ fused QKV projection: A(4096x1152) @ [Wq|Wk|Wv]^T (3456 cols)
// PINNED round-12 body (131us, VGPR 60, MfmaUtil 33%): 128x128, 1D grid
// 864 = 8 XCD x 108 bijective swizzle, direct LDS staging, LK=40, (256,2).
// CLOSED after 6 structural attempts (see round 5/8/10/12/13 post-mortems).
__global__ __launch_bounds__(256, 2) void k_pgemm3(
    const short* __restrict__ Ah_g, const short* __restrict__ Al_g,
    const short* __restrict__ Bh_g, const short* __restrict__ Bl_g,
    short* __restrict__ QKV0)
{
  constexpr int LK = 40;   // 32 k + 8 pad
  __shared__ short AhS[128 * LK], AlS[128 * LK], BhS[128 * LK], BlS[128 * LK];
  const int tid = threadIdx.x;
  const int wv = tid >> 6, ln = tid & 63;
  const int col = ln & 31, hi = ln >> 5;
  const int wm = wv >> 1, wn = wv & 1;
  const int swz = (blockIdx.x & 7) * 108 + (blockIdx.x >> 3);
  const int m0 = (swz / 27) * 128, n0 = (swz % 27) * 128;

  f32x16 acc[2][2];
#pragma unroll
  for (int mi = 0; mi < 2; ++mi)
#pragma unroll
    for (int ni = 0; ni < 2; ++ni)
#pragma unroll
      for (int r = 0; r < 16; ++r) acc[mi][ni][r] = 0.f;

  for (int kt = 0; kt < 1152; kt += 32) {
    __syncthreads();
    for (int e = tid; e < 512; e += 256) {
      int r = e >> 2, c4 = e & 3;
      size_t sa = (size_t)(m0 + r) * 1152 + kt + c4 * 8;
      *(float4*)&AhS[r * LK + c4 * 8] = *(const float4*)(Ah_g + sa);
      *(float4*)&AlS[r * LK + c4 * 8] = *(const float4*)(Al_g + sa);
      size_t sb = (size_t)(n0 + r) * 1152 + kt + c4 * 8;
      *(float4*)&BhS[r * LK + c4 * 8] = *(const float4*)(Bh_g + sb);
      *(float4*)&BlS[r * LK + c4 * 8] = *(const float4*)(Bl_g + sb);
    }
    __syncthreads();
#pragma unroll
    for (int kc = 0; kc < 2; ++kc) {
      bf16x8 ah[2], al[2], bh[2], bl[2];
#pragma unroll
      for (int mi = 0; mi < 2; ++mi) {
        int r = wm * 64 + mi * 32 + col;
        ah[mi] = *(const bf16x8*)&AhS[r * LK + kc * 16 + hi * 8];
        al[mi] = *(const bf16x8*)&AlS[r * LK + kc * 16 + hi * 8];
      }
#pragma unroll
      for (int ni = 0; ni < 2; ++ni) {
        int r = wn * 64 + ni * 32 + col;
        bh[ni] = *(const bf16x8*)&BhS[r * LK + kc * 16 + hi * 8];
        bl[ni] = *(const bf16x8*)&BlS[r * LK + kc * 16 + hi * 8];
      }
#pragma unroll
      for (int mi = 0; mi < 2; ++mi)
#pragma unroll
        for (int ni = 0; ni < 2; ++ni) {
          acc[mi][ni] = mfma_bf16(ah[mi], bh[ni], acc[mi][ni]);
          acc[mi][ni] = mfma_bf16(ah[mi], bl[ni], acc[mi][ni]);
          acc[mi][ni] = mfma_bf16(al[mi], bh[ni], acc[mi][ni]);
        }
    }
  }
  const size_t S = (size_t)65536 * 80;   // elements per QKV hi (or lo) array
#pragma unroll
  for (int mi = 0; mi < 2; ++mi)
#pragma unroll
    for (int ni = 0; ni < 2; ++ni)
#pragma unroll
      for (int r = 0; r < 16; ++r) {
        int m = m0 + wm * 64 + mi * 32 + (r & 3) + 8 * (r >> 2) + 4 * hi;
        int c = n0 + wn * 64 + ni * 32 + col;
        int which = c / 1152, cm = c - which * 1152;
        int hh = cm / 72, dd = cm - hh * 72;
        int b = m >> 11, nn = m & 2047;
        size_t idx = (((size_t)(b * 16 + hh)) * 2048 + nn) * 80 + dd;
        float v = acc[mi][ni][r];
        short hb = f2bf(v);
        short* OH = QKV0 + (size_t)which * 2 * S;
        OH[idx] = hb;
        OH[S + idx] = f2bf(v - bf2f(hb));
      }
}

// ------------- softmax denominator PARTIALS via MFMA, q-tile 256, k-half
__global__ __launch_bounds__(256, 2) void k_stats3(
    const short* __restrict__ Qh, const short* __restrict__ Ql,
    const short* __restrict__ Kh, const short* __restrict__ Kl,
    float* __restrict__ ssum)
{
  __shared__ __align__(16) short kh[64 * LSTR];
  __shared__ __align__(16) short kl[64 * LSTR];
  const int tid = threadIdx.x;
  const int wv = tid >> 6, ln = tid & 63;
  const int col = ln & 31, hi = ln >> 5;
  const int hb = blockIdx.x & 31;
  const int rest = blockIdx.x >> 5;
  const int q0 = (rest & 7) * 256;
  const int ks = rest >> 3;               // 0 or 1
  const int h = hb >> 1, b = hb & 1;
  const size_t bhbase = (size_t)(b * H + h) * N * DP;
  const int kbeg = ks * (N / 2), kend = kbeg + N / 2;

  bf16x8 qfh[2][5], qfl[2][5];
#pragma unroll
  for (int mi = 0; mi < 2; ++mi) {
    const size_t rb = bhbase + (size_t)(q0 + wv * 64 + mi * 32 + col) * DP + hi * 8;
#pragma unroll
    for (int d = 0; d < 5; ++d) {
      qfh[mi][d] = *(const bf16x8*)(const void*)(Qh + rb + d * 16);
      qfl[mi][d] = *(const bf16x8*)(const void*)(Ql + rb + d * 16);
    }
  }
  float s[2][16];
#pragma unroll
  for (int mi = 0; mi < 2; ++mi)
#pragma unroll
    for (int r = 0; r < 16; ++r) s[mi][r] = 0.f;

  float4 rkh[3], rkl[3];
  auto LOADK = [&](int kt) {
#pragma unroll
    for (int ss = 0; ss < 3; ++ss) {
      int e = ss * 256 + tid;
      if (e < 640) {
        int r = e / 10, cc = e - r * 10;
        size_t sb = bhbase + (size_t)(kt + r) * DP + cc * 8;
        rkh[ss] = *(const float4*)(const void*)(Kh + sb);
        rkl[ss] = *(const float4*)(const void*)(Kl + sb);
      }
    }
  };
  auto STOREK = [&]() {
#pragma unroll
    for (int ss = 0; ss < 3; ++ss) {
      int e = ss * 256 + tid;
      if (e < 640) {
        int r = e / 10, cc = e - r * 10;
        *(float4*)(void*)(kh + r * LSTR + cc * 8) = rkh[ss];
        *(float4*)(void*)(kl + r * LSTR + cc * 8) = rkl[ss];
      }
    }
  };

  LOADK(kbeg);
  for (int kt = kbeg; kt < kend; kt += 64) {
    __syncthreads();
    STOREK();
    __syncthreads();
    if (kt + 64 < kend) LOADK(kt + 64);
    f32x16 z[2][2];
#pragma unroll
    for (int mi = 0; mi < 2; ++mi)
#pragma unroll
      for (int rn = 0; rn < 2; ++rn)
#pragma unroll
        for (int r = 0; r < 16; ++r) z[mi][rn][r] = 0.f;
#pragma unroll
    for (int d = 0; d < 5; ++d) {
      const int boff = d * 16 + hi * 8;
      bf16x8 bh0 = *(const bf16x8*)(const void*)(kh + col * LSTR + boff);
      bf16x8 bl0 = *(const bf16x8*)(const void*)(kl + col * LSTR + boff);
      bf16x8 bh1 = *(const bf16x8*)(const void*)(kh + (32 + col) * LSTR + boff);
      bf16x8 bl1 = *(const bf16x8*)(const void*)(kl + (32 + col) * LSTR + boff);
#pragma unroll
      for (int mi = 0; mi < 2; ++mi) {
        z[mi][0] = mfma_bf16(qfh[mi][d], bh0, z[mi][0]);
        z[mi][0] = mfma_bf16(qfh[mi][d], bl0, z[mi][0]);
        z[mi][0] = mfma_bf16(qfl[mi][d], bh0, z[mi][0]);
        z[mi][1] = mfma_bf16(qfh[mi][d], bh1, z[mi][1]);
        z[mi][1] = mfma_bf16(qfh[mi][d], bl1, z[mi][1]);
        z[mi][1] = mfma_bf16(qfl[mi][d], bh1, z[mi][1]);
      }
    }
#pragma unroll
    for (int mi = 0; mi < 2; ++mi)
#pragma unroll
      for (int r = 0; r < 16; ++r)
        s[mi][r] += __expf(z[mi][0][r] * SCALE) + __expf(z[mi][1][r] * SCALE);
  }
#pragma unroll
  for (int mi = 0; mi < 2; ++mi)
#pragma unroll
    for (int r = 0; r < 16; ++r) {
      float v = s[mi][r];
#pragma unroll
      for (int o = 1; o < 32; o <<= 1) v += __shfl_xor(v, o);
      if (col == 0) {
        int row = q0 + wv * 64 + mi * 32 + ((r & 3) + ((r >> 2) << 3) + (hi << 2));
        ssum[(size_t)ks * ROWS + (size_t)(b * H + h) * N + row] = v;
      }
    }
}

// ---- combine the 2 k-half partials into inv (fixed order, deterministic)
__global__ __launch_bounds__(256) void k_sinv(
    const float* __restrict__ ssum, float* __restrict__ inv_out)
{
  int g = blockIdx.x * 256 + threadIdx.x;
  if (g < ROWS) inv_out[g] = 1.0f / (ssum[g] + ssum[(size_t)ROWS + g]);
}

// --------------- head-averaged attention matrix, q-tile 256 x k-tile 64
__global__ __launch_bounds__(256, 2) void k_attn3(
    const short* __restrict__ Qh, const short* __restrict__ Ql,
    const short* __restrict__ Kh, const short* __restrict__ Kl,
    const float* __restrict__ inv_in, float* __restrict__ attn,
    float* __restrict__ part8)
{
  __shared__ __align__(16) short kh[64 * LSTR];
  __shared__ __align__(16) short kl[64 * LSTR];
  __shared__ float invs[256];
  __shared__ float colred[64][8];
  const int tid = threadIdx.x;
  const int wv = tid >> 6, ln = tid & 63;
  const int col = ln & 31, hi = ln >> 5;
  const int q0 = (blockIdx.x & 7) * 256;
  const int b = (blockIdx.x >> 3) & 1;
  const int k0 = (blockIdx.x >> 4) * 64;

  f32x16 pa[2][2];
#pragma unroll
  for (int mi = 0; mi < 2; ++mi)
#pragma unroll
    for (int rn = 0; rn < 2; ++rn)
#pragma unroll
      for (int r = 0; r < 16; ++r) pa[mi][rn][r] = 0.f;

  float4 rkh[3], rkl[3];
  float rin;
  auto LOADH = [&](int h) {
    const size_t hb = (size_t)(b * H + h) * N * DP;
#pragma unroll
    for (int ss = 0; ss < 3; ++ss) {
      int e = ss * 256 + tid;
      if (e < 640) {
        int r = e / 10, cc = e - r * 10;
        size_t sb = hb + (size_t)(k0 + r) * DP + cc * 8;
        rkh[ss] = *(const float4*)(const void*)(Kh + sb);
        rkl[ss] = *(const float4*)(const void*)(Kl + sb);
      }
    }
    rin = inv_in[(size_t)(b * H + h) * N + q0 + tid];
  };
  auto STOREH = [&]() {
#pragma unroll
    for (int ss = 0; ss < 3; ++ss) {
      int e = ss * 256 + tid;
      if (e < 640) {
        int r = e / 10, cc = e - r * 10;
        *(float4*)(void*)(kh + r * LSTR + cc * 8) = rkh[ss];
        *(float4*)(void*)(kl + r * LSTR + cc * 8) = rkl[ss];
      }
    }
    invs[tid] = rin;
  };

  LOADH(0);
  for (int h = 0; h < H; ++h) {
    __syncthreads();
    STOREH();
    __syncthreads();
    if (h + 1 < H) LOADH(h + 1);

    const size_t bhbase = (size_t)(b * H + h) * N * DP;
    f32x16 z[2][2];
#pragma unroll
    for (int mi = 0; mi < 2; ++mi)
#pragma unroll
      for (int rn = 0; rn < 2; ++rn)
#pragma unroll
        for (int r = 0; r < 16; ++r) z[mi][rn][r] = 0.f;

#pragma unroll
    for (int d = 0; d < 5; ++d) {
      const int boff = d * 16 + hi * 8;
      bf16x8 bh0 = *(const bf16x8*)(const void*)(kh + col * LSTR + boff);
      bf16x8 bl0 = *(const bf16x8*)(const void*)(kl + col * LSTR + boff);
      bf16x8 bh1 = *(const bf16x8*)(const void*)(kh + (32 + col) * LSTR + boff);
      bf16x8 bl1 = *(const bf16x8*)(const void*)(kl + (32 + col) * LSTR + boff);
      bf16x8 qh0 = *(const bf16x8*)(const void*)(Qh + bhbase + (size_t)(q0 + wv * 64 + col) * DP + boff);
      bf16x8 ql0 = *(const bf16x8*)(const void*)(Ql + bhbase + (size_t)(q0 + wv * 64 + col) * DP + boff);
      bf16x8 qh1 = *(const bf16x8*)(const void*)(Qh + bhbase + (size_t)(q0 + wv * 64 + 32 + col) * DP + boff);
      bf16x8 ql1 = *(const bf16x8*)(const void*)(Ql + bhbase + (size_t)(q0 + wv * 64 + 32 + col) * DP + boff);
      z[0][0] = mfma_bf16(qh0, bh0, z[0][0]);
      z[0][0] = mfma_bf16(qh0, bl0, z[0][0]);
      z[0][0] = mfma_bf16(ql0, bh0, z[0][0]);
      z[0][1] = mfma_bf16(qh0, bh1, z[0][1]);
      z[0][1] = mfma_bf16(qh0, bl1, z[0][1]);
      z[0][1] = mfma_bf16(ql0, bh1, z[0][1]);
      z[1][0] = mfma_bf16(qh1, bh0, z[1][0]);
      z[1][0] = mfma_bf16(qh1, bl0, z[1][0]);
      z[1][0] = mfma_bf16(ql1, bh0, z[1][0]);
      z[1][1] = mfma_bf16(qh1, bh1, z[1][1]);
      z[1][1] = mfma_bf16(qh1, bl1, z[1][1]);
      z[1][1] = mfma_bf16(ql1, bh1, z[1][1]);
    }
#pragma unroll
    for (int mi = 0; mi < 2; ++mi)
#pragma unroll
      for (int r = 0; r < 16; ++r) {
        const int rloc = wv * 64 + mi * 32 + (r & 3) + ((r >> 2) << 3) + (hi << 2);
        const float iv = invs[rloc];
        pa[mi][0][r] += __expf(z[mi][0][r] * SCALE) * iv;
        pa[mi][1][r] += __expf(z[mi][1][r] * SCALE) * iv;
      }
  }
  const float invH = 1.0f / H;
#pragma unroll
  for (int mi = 0; mi < 2; ++mi)
#pragma unroll
    for (int r = 0; r < 16; ++r) {
      const int row = q0 + wv * 64 + mi * 32 + (r & 3) + ((r >> 2) << 3) + (hi << 2);
      attn[((size_t)b * N + row) * N + k0 + col] = pa[mi][0][r] * invH;
      attn[((size_t)b * N + row) * N + k0 + 32 + col] = pa[mi][1][r] * invH;
    }
  // ---- first matvec partials: per-column sum over this block's 256 rows
  __syncthreads();
#pragma unroll
  for (int rn = 0; rn < 2; ++rn) {
    float s = 0.f;
#pragma unroll
    for (int mi = 0; mi < 2; ++mi)
#pragma unroll
      for (int r = 0; r < 16; ++r) s += pa[mi][rn][r];
    colred[rn * 32 + col][wv * 2 + hi] = s * invH;
  }
  __syncthreads();
  if (tid < 64) {
    float s = 0.f;
#pragma unroll
    for (int u = 0; u < 8; ++u) s += colred[tid][u];
    part8[(size_t)(q0 >> 8) * (B * N) + b * N + k0 + tid] = s * (1.0f / N);
  }
}

// matvec step: reduce nin slices of partial_in for this block's 64 rows, matvec
// 4-way split accumulator breaks the serial FMA dependency chain.
__global__ __launch_bounds__(256) void k_powfused(
    const float* __restrict__ attn, const float* __restrict__ partial_in,
    float* __restrict__ partial_out, int nin)
{
  __shared__ float red[4][64];
  __shared__ float ds[64];
  const int tid = threadIdx.x;
  const int g = blockIdx.x * 256 + tid;
  const int sy = blockIdx.y;
  const int b = g / N, j = g % N;
  const int i0 = sy * ILEN;
  {
    int i = tid & 63, sgrp = tid >> 6;
    const int per = nin >> 2;
    const float* p = partial_in + (size_t)(b * N + i0 + i);
    float s8 = 0.f;
    for (int k = 0; k < per; ++k) s8 += p[(size_t)(sgrp * per + k) * (B * N)];
    red[sgrp][i] = s8;
  }
  __syncthreads();
  if (tid < 64) ds[tid] = red[0][tid] + red[1][tid] + red[2][tid] + red[3][tid];
  __syncthreads();
  const float* ab = attn + (size_t)b * N * N;
  float s0 = 0.f, s1 = 0.f, s2 = 0.f, s3 = 0.f;
  for (int i = 0; i < ILEN; i += 4) {
    s0 += ds[i + 0] * ab[(size_t)(i0 + i + 0) * N + j];
    s1 += ds[i + 1] * ab[(size_t)(i0 + i + 1) * N + j];
    s2 += ds[i + 2] * ab[(size_t)(i0 + i + 2) * N + j];
    s3 += ds[i + 3] * ab[(size_t)(i0 + i + 3) * N + j];
  }
  partial_out[(size_t)sy * (B * N) + g] = (s0 + s1) + (s2 + s3);
}

// ------- top-k partition (bitonic sort); input = 32-slice partial vector
__global__ __launch_bounds__(1024) void k_partition(
    const float* __restrict__ partial, int* __restrict__ sorted_imp,
    int* __restrict__ keepflag, int* __restrict__ s_map)
{
  __shared__ float v[N];
  __shared__ int   id[N];
  __shared__ int   kf[N];
  __shared__ int   ps[N];
  const int tid = threadIdx.x;
  const int b = blockIdx.x;
  for (int i = tid; i < N; i += 1024) {
    float s = 0.f;
    const float* p = partial + (size_t)(b * N + i);
    for (int sy = 0; sy < PSL; ++sy) s += p[(size_t)sy * (B * N)];
    v[i] = s; id[i] = i;
  }
  for (int k = 2; k <= N; k <<= 1) {
    for (int j = k >> 1; j > 0; j >>= 1) {
      __syncthreads();
      for (int i = tid; i < N; i += 1024) {
        int ixj = i ^ j;
        if (ixj > i) {
          bool up = ((i & k) == 0);
          float va = v[i], vb = v[ixj];
          int ia = id[i], ib = id[ixj];
          bool b_before_a = (vb > va) || (vb == va && ib < ia);
          if (b_before_a == up) { v[i] = vb; v[ixj] = va; id[i] = ib; id[ixj] = ia; }
        }
      }
    }
  }
  __syncthreads();
  for (int i = tid; i < N; i += 1024) kf[id[i]] = (i < NKEEP) ? 1 : 0;
  __syncthreads();
  for (int i = tid; i < N; i += 1024) ps[i] = kf[i];
  for (int off = 1; off < N; off <<= 1) {
    __syncthreads();
    int t0 = (tid >= off) ? ps[tid - off] : 0;
    int i1 = tid + 1024;
    int t1 = ps[i1 - off];
    __syncthreads();
    ps[tid] += t0;
    ps[i1] += t1;
  }
  __syncthreads();
  for (int i = tid; i < N; i += 1024) {
    int excl = ps[i] - kf[i];
    keepflag[b * N + i] = kf[i];
    if (kf[i]) { sorted_imp[b * NKEEP + excl] = i; s_map[b * N + i] = excl; }
  }
}

// --------------- per-column argmax over kept rows, sliced (16x parallelism)
__global__ __launch_bounds__(256) void k_argmax_part(
    const float* __restrict__ attn, const int* __restrict__ sorted_imp,
    float* __restrict__ pval, int* __restrict__ pidx)
{
  __shared__ int imp_s[ACH];
  const int tid = threadIdx.x;
  const int g = blockIdx.x * 256 + tid;
  const int s = blockIdx.y;
  const int b = g / N, n = g % N;
  const int k0 = s * ACH;
  const int k1 = (k0 + ACH < NKEEP) ? k0 + ACH : NKEEP;
  const int cnt = k1 - k0;
  for (int i = tid; i < cnt; i += 256) imp_s[i] = sorted_imp[b * NKEEP + k0 + i];
  __syncthreads();
  const float* ab = attn + (size_t)b * N * N;
  float best = -FINF; int bi = k0;
  for (int k = 0; k < cnt; ++k) {
    float val = ab[(size_t)imp_s[k] * N + n];
    if (val > best) { best = val; bi = k0 + k; }   // strict >: first max
  }
  pval[(size_t)s * (B * N) + g] = best;
  pidx[(size_t)s * (B * N) + g] = bi;
}

// combine ascending: strict > keeps earliest k on ties (jnp.argmax semantics)
__global__ __launch_bounds__(256) void k_argmax_comb(
    const float* __restrict__ pval, const int* __restrict__ pidx,
    const int* __restrict__ keepflag, int* __restrict__ s_map)
{
  int g = blockIdx.x * 256 + threadIdx.x;
  if (g >= B * N) return;
  float best = -FINF; int bi = 0;
#pragma unroll
  for (int s = 0; s < ASL; ++s) {
    float v = pval[(size_t)s * (B * N) + g];
    if (v > best) { best = v; bi = pidx[(size_t)s * (B * N) + g]; }
  }
  if (!keepflag[g]) s_map[g] = bi;
}

// -------- fused reduced attention: gathered QK^T + softmax + PV (MFMA)
__global__ __launch_bounds__(256, 2) void k_rfused(
    const short* __restrict__ Qh, const short* __restrict__ Ql,
    const short* __restrict__ Kh, const short* __restrict__ Kl,
    const short* __restrict__ Vh, const int* __restrict__ sorted_imp,
    short* __restrict__ Yh, short* __restrict__ Yl)
{
  constexpr int LK = 88;
  constexpr int VTS = 72;
  __shared__ __align__(16) short KhS[64 * LK];
  __shared__ __align__(16) short KlS[64 * LK];
  __shared__ __align__(16) short VhS[64 * LK];
  __shared__ __align__(16) short VT[72 * VTS];
  __shared__ int imp[NKEEP];
  const int tid = threadIdx.x;
  const int wv = tid >> 6, ln = tid & 63;
  const int col = ln & 31, hi = ln >> 5;
  const int b = blockIdx.z, h = blockIdx.y, q0 = blockIdx.x * 128;
  const size_t bh80 = (size_t)(b * H + h) * N * DP;
  for (int i = tid; i < NKEEP; i += 256) imp[i] = sorted_imp[b * NKEEP + i];
  __syncthreads();
  int qr = q0 + wv * 32 + col;
  int qi = imp[qr < NKEEP ? qr : NKEEP - 1];
  bf16x8 qfh[5], qfl[5];
  {
    const size_t qb = bh80 + (size_t)qi * DP + hi * 8;
#pragma unroll
    for (int d = 0; d < 5; ++d) {
      qfh[d] = *(const bf16x8*)(const void*)(Qh + qb + d * 16);
      qfl[d] = *(const bf16x8*)(const void*)(Ql + qb + d * 16);
    }
  }
  float denom = 0.f;
  f32x16 oacc[3];
#pragma unroll
  for (int nc = 0; nc < 3; ++nc)
#pragma unroll
    for (int r = 0; r < 16; ++r) oacc[nc][r] = 0.f;

  for (int kt = 0; kt < 832; kt += 64) {
    for (int e = tid; e < 640; e += 256) {
      int r = e / 10, cc = e - r * 10;
      int kv = kt + r;
      float4 vkh, vkl, vvh;
      if (kv < NKEEP) {
        size_t sb = bh80 + (size_t)imp[kv] * DP + cc * 8;
        vkh = *(const float4*)(const void*)(Kh + sb);
        vkl = *(const float4*)(const void*)(Kl + sb);
        vvh = *(const float4*)(const void*)(Vh + sb);
      } else {
        vkh = make_float4(0.f, 0.f, 0.f, 0.f); vkl = vkh; vvh = vkh;
      }
      *(float4*)(void*)&KhS[r * LK + cc * 8] = vkh;
      *(float4*)(void*)&KlS[r * LK + cc * 8] = vkl;
      *(float4*)(void*)&VhS[r * LK + cc * 8] = vvh;
    }
    __syncthreads();
    f32x16 z[2];
#pragma unroll
    for (int rn = 0; rn < 2; ++rn)
#pragma unroll
      for (int r = 0; r < 16; ++r) z[rn][r] = 0.f;
#pragma unroll
    for (int d = 0; d < 5; ++d) {
      const int boff = d * 16 + hi * 8;
#pragma unroll
      for (int rn = 0; rn < 2; ++rn) {
        bf16x8 kfh = *(const bf16x8*)(const void*)(KhS + (rn * 32 + col) * LK + boff);
        bf16x8 kfl = *(const bf16x8*)(const void*)(KlS + (rn * 32 + col) * LK + boff);
        z[rn] = mfma_bf16(kfh, qfh[d], z[rn]);
        z[rn] = mfma_bf16(kfh, qfl[d], z[rn]);
        z[rn] = mfma_bf16(kfl, qfh[d], z[rn]);
      }
    }
    for (int e = tid; e < 576; e += 256) {
      int dd = e % 72, k8 = e / 72;
      short8 t;
#pragma unroll
      for (int j = 0; j < 8; ++j) t[j] = VhS[(k8 * 8 + j) * LK + dd];
      *(short8*)(void*)&VT[dd * VTS + k8 * 8] = t;
    }
    const bool full = (kt + 64 <= NKEEP);
#pragma unroll
    for (int rn = 0; rn < 2; ++rn) {
      int kvb = kt + rn * 32 + 4 * hi;
#pragma unroll
      for (int r = 0; r < 16; ++r) {
        float pe = __expf(z[rn][r] * SCALE);
        if (!full) {
          int kv = kvb + (r & 3) + 8 * (r >> 2);
          pe = (kv < NKEEP) ? pe : 0.f;
        }
        z[rn][r] = pe;
        denom += pe;
      }
    }
    __syncthreads();
#pragma unroll
    for (int rn = 0; rn < 2; ++rn) {
#pragma unroll
      for (int kc = 0; kc < 2; ++kc) {
        unsigned p0, p1, p2, p3;
        asm("v_cvt_pk_bf16_f32 %0, %1, %2" : "=v"(p0) : "v"(z[rn][8 * kc + 0]), "v"(z[rn][8 * kc + 1]));
        asm("v_cvt_pk_bf16_f32 %0, %1, %2" : "=v"(p1) : "v"(z[rn][8 * kc + 2]), "v"(z[rn][8 * kc + 3]));
        asm("v_cvt_pk_bf16_f32 %0, %1, %2" : "=v"(p2) : "v"(z[rn][8 * kc + 4]), "v"(z[rn][8 * kc + 5]));
        asm("v_cvt_pk_bf16_f32 %0, %1, %2" : "=v"(p3) : "v"(z[rn][8 * kc + 6]), "v"(z[rn][8 * kc + 7]));
        unsigned othA = hi ? p0 : p2, othB = hi ? p1 : p3;
        unsigned swA = (unsigned)__shfl_xor((int)othA, 32);
        unsigned swB = (unsigned)__shfl_xor((int)othB, 32);
        union { unsigned u[4]; bf16x8 v; } pf;
        pf.u[0] = hi ? swA : p0; pf.u[1] = hi ? swB : p1;
        pf.u[2] = hi ? p2 : swA; pf.u[3] = hi ? p3 : swB;
        const int kb = rn * 32 + kc * 16 + hi * 8;
#pragma unroll
        for (int nc = 0; nc < 3; ++nc) {
          int dr = nc * 32 + col; if (dr > 71) dr = 71;
          bf16x8 vf = *(const bf16x8*)(const void*)(VT + dr * VTS + kb);
          oacc[nc] = mfma_bf16(pf.v, vf, oacc[nc]);
        }
      }
    }
  }
  denom += __shfl_xor(denom, 32);
  float invd = 1.0f / denom;
#pragma unroll
  for (int r = 0; r < 16; ++r) {
    int cr = (r & 3) + 8 * (r >> 2) + 4 * hi;
    int q = q0 + wv * 32 + cr;
    float dv = __shfl(invd, cr);
    if (q < NKEEP) {
#pragma unroll
      for (int nc = 0; nc < 3; ++nc) {
        int dd = nc * 32 + col;
        if (dd < 72) {
          float v = oacc[nc][r] * dv;
          size_t idx = ((size_t)b * NKEEP + q) * 1152 + h * 72 + dd;
          short hb = f2bf(v);
          Yh[idx] = hb;
          Yl[idx] = f2bf(v - bf2f(hb));
        }
      }
    }
  }
}

// ---- output projection, SCATTERED epilogue: writes kept rows directly into
// out[b][sorted_imp[m]] (rows are 4.6KB contiguous -> coalescing preserved)
__global__ __launch_bounds__(256, 2) void k_ogemm(
    const short* __restrict__ Ah_g, const short* __restrict__ Al_g,
    const short* __restrict__ Bh_g, const short* __restrict__ Bl_g,
    const int* __restrict__ sorted_imp,
    float* __restrict__ OutF, const float* __restrict__ bias,
    int Mtot)
{
  constexpr int LK = 40;
  __shared__ short AhS[64 * LK], AlS[64 * LK], BhS[64 * LK], BlS[64 * LK];
  const int tid = threadIdx.x;
  const int wv = tid >> 6, ln = tid & 63;
  const int col = ln & 31, hi = ln >> 5;
  const int wm = wv >> 1, wn = wv & 1;
  const int m0 = blockIdx.y * 64, n0 = blockIdx.x * 64;
  f32x16 acc;
#pragma unroll
  for (int r = 0; r < 16; ++r) acc[r] = 0.f;

  for (int kt = 0; kt < 1152; kt += 32) {
    __syncthreads();
    {
      int e = tid;
      int r = e >> 2, c4 = e & 3;
      int ra = m0 + r; if (ra >= Mtot) ra = Mtot - 1;
      size_t sa = (size_t)ra * 1152 + kt + c4 * 8;
      *(float4*)&AhS[r * LK + c4 * 8] = *(const float4*)(Ah_g + sa);
      *(float4*)&AlS[r * LK + c4 * 8] = *(const float4*)(Al_g + sa);
      size_t sb = (size_t)(n0 + r) * 1152 + kt + c4 * 8;
      *(float4*)&BhS[r * LK + c4 * 8] = *(const float4*)(Bh_g + sb);
      *(float4*)&BlS[r * LK + c4 * 8] = *(const float4*)(Bl_g + sb);
    }
    __syncthreads();
#pragma unroll
    for (int kc = 0; kc < 2; ++kc) {
      int ra = wm * 32 + col;
      int rb = wn * 32 + col;
      bf16x8 ah = *(const bf16x8*)&AhS[ra * LK + kc * 16 + hi * 8];
      bf16x8 al = *(const bf16x8*)&AlS[ra * LK + kc * 16 + hi * 8];
      bf16x8 bh = *(const bf16x8*)&BhS[rb * LK + kc * 16 + hi * 8];
      bf16x8 bl = *(const bf16x8*)&BlS[rb * LK + kc * 16 + hi * 8];
      acc = mfma_bf16(ah, bh, acc);
      acc = mfma_bf16(ah, bl, acc);
      acc = mfma_bf16(al, bh, acc);
    }
  }
#pragma unroll
  for (int r = 0; r < 16; ++r) {
    int m = m0 + wm * 32 + (r & 3) + 8 * (r >> 2) + 4 * hi;
    int c = n0 + wn * 32 + col;
    if (m < Mtot) {
      int b = m / NKEEP, mm = m - b * NKEEP;
      int orig = sorted_imp[b * NKEEP + mm];
      OutF[((size_t)b * N + orig) * 1152 + c] = acc[r] + bias[c];
    }
  }
}

// ---- pruned-row copy: out[b][n] = out[b][sorted_imp[s_map[n]]] for !kept
// (reads only kept rows written by k_ogemm; writes only pruned rows -> no race)
__global__ __launch_bounds__(256) void k_prune(
    const int* __restrict__ keepflag, const int* __restrict__ sorted_imp,
    const int* __restrict__ s_map, float* __restrict__ out)
{
  size_t g = (size_t)blockIdx.x * 256 + threadIdx.x;
  if (g >= (size_t)B * N * QD) return;
  int c = (int)(g % QD);
  int n_ = (int)((g / QD) % N);
  int b = (int)(g / ((size_t)N * QD));
  if (keepflag[b * N + n_]) return;
  int src = sorted_imp[b * NKEEP + s_map[b * N + n_]];
  out[g] = out[((size_t)b * N + src) * QD + c];
}

// ---------------------------------------------------------------- launch
extern "C" void kernel_launch(void* const* d_in, const int* in_sizes, int n_in,
                              void* d_out, int out_size, void* d_ws, size_t ws_size,
                              hipStream_t stream)
{
  const float* x  = (const float*)d_in[0];
  const float* Wq = (const float*)d_in[1];
  const float* Wk = (const float*)d_in[2];
  const float* Wv = (const float*)d_in[3];
  const float* Wo = (const float*)d_in[4];
  const float* bo = (const float*)d_in[5];
  float* out = (float*)d_out;

  char* ws = (char*)d_ws;
  size_t off = 0;
  auto alloc = [&](size_t bytes) -> void* {
    void* p = ws + off;
    off = (off + bytes + 255) & ~(size_t)255;
    return p;
  };
  const size_t XEL = (size_t)B * N * QD;    // 4718592
  const size_t WEL = (size_t)QD * INNER;    // 1327104
  short* xh   = (short*)alloc(sizeof(short) * XEL);
  short* xl   = (short*)alloc(sizeof(short) * XEL);
  short* WTh  = (short*)alloc(sizeof(short) * WEL * 3);   // [Wq|Wk|Wv]^T hi
  short* WTl  = (short*)alloc(sizeof(short) * WEL * 3);   // lo
  short* WoTh = (short*)alloc(sizeof(short) * WEL);
  short* WoTl = (short*)alloc(sizeof(short) * WEL);
  short* Qhb  = (short*)alloc(sizeof(short) * (size_t)ROWS * DP);
  short* Qlb  = (short*)alloc(sizeof(short) * (size_t)ROWS * DP);
  short* Khb  = (short*)alloc(sizeof(short) * (size_t)ROWS * DP);
  short* Klb  = (short*)alloc(sizeof(short) * (size_t)ROWS * DP);
  short* Vhb  = (short*)alloc(sizeof(short) * (size_t)ROWS * DP);
  short* Vlb  = (short*)alloc(sizeof(short) * (size_t)ROWS * DP);
  float* attn = (float*)alloc(sizeof(float) * (size_t)B * N * N);
  float* ssum = (float*)alloc(sizeof(float) * 2 * (size_t)ROWS);
  float* inv  = (float*)alloc(sizeof(float) * (size_t)ROWS);
  float* partA = (float*)alloc(sizeof(float) * PSL * B * N);
  float* partB = (float*)alloc(sizeof(float) * PSL * B * N);
  int* sorted_imp = (int*)alloc(sizeof(int) * B * NKEEP);
  int* keepflag   = (int*)alloc(sizeof(int) * B * N);
  int* s_map      = (int*)alloc(sizeof(int) * B * N);
  float* pval     = (float*)alloc(sizeof(float) * ASL * B * N);
  int*   pidx     = (int*)alloc(sizeof(int) * ASL * B * N);
  (void)Vlb;
  // aliases into dead regions:
  short* Yh = xh;
  short* Yl = xh + (size_t)B * NKEEP * INNER;

  dim3 blk(256);

  // prep: vectorized x split + QKV pad zeroing (exact grid), W splits (1 launch)
  k_prep<<<dim3((X4 + 6 * ROWS) / 256), blk, 0, stream>>>(x, xh, xl, Qhb);
  k_wsplit4<<<dim3(QD / 64, QD / 64, 4), blk, 0, stream>>>(
      Wq, Wk, Wv, Wo, WTh, WTl, WoTh, WoTl);

  // fused QKV projection (1D grid 864, XCD-swizzled, direct staging — pinned)
  k_pgemm3<<<dim3(864), blk, 0, stream>>>(xh, xl, WTh, WTl, Qhb);

  // full attention: denominator partials (k-split, 512 blocks) + combine +
  // head-averaged matrix (+ first matvec into partB)
  k_stats3<<<dim3(512), blk, 0, stream>>>(Qhb, Qlb, Khb, Klb, ssum);
  k_sinv<<<dim3(ROWS / 256), blk, 0, stream>>>(ssum, inv);
  k_attn3<<<dim3(512), blk, 0, stream>>>(Qhb, Qlb, Khb, Klb, inv, attn, partB);

  // remaining 4 power-iteration matvecs; partition reduces the final 32 slices
  k_powfused<<<dim3(B * N / 256, PSL), blk, 0, stream>>>(attn, partB, partA, 8);
  k_powfused<<<dim3(B * N / 256, PSL), blk, 0, stream>>>(attn, partA, partB, 32);
  k_powfused<<<dim3(B * N / 256, PSL), blk, 0, stream>>>(attn, partB, partA, 32);
  k_powfused<<<dim3(B * N / 256, PSL), blk, 0, stream>>>(attn, partA, partB, 32);

  // top-k partition (folds final 32-slice reduce) + sliced per-column argmax
  k_partition<<<dim3(B), dim3(1024), 0, stream>>>(partB, sorted_imp, keepflag, s_map);
  k_argmax_part<<<dim3(B * N / 256, ASL), blk, 0, stream>>>(attn, sorted_imp, pval, pidx);
  k_argmax_comb<<<dim3(B * N / 256), blk, 0, stream>>>(pval, pidx, keepflag, s_map);

  // fused reduced attention (writes Yh/Yl into dead xh region)
  k_rfused<<<dim3((NKEEP + 127) / 128, H, B), blk, 0, stream>>>(
      Qhb, Qlb, Khb, Klb, Vhb, sorted_imp, Yh, Yl);

  // output projection scatter-writes kept rows into out; prune copies the rest
  k_ogemm<<<dim3(QD / 64, (B * NKEEP + 63) / 64), blk, 0, stream>>>(
      Yh, Yl, WoTh, WoTl, sorted_imp, out, bo, B * NKEEP);
  k_prune<<<dim3((int)(((size_t)B * N * QD + 255) / 256)), blk, 0, stream>>>(
      keepflag, sorted_imp, s_map, out);
}

// Round 18
// 494.000 us; speedup vs baseline: 1.0187x; 1.0187x over previous
//
#include <hip/hip_runtime.h>

namespace {
constexpr int B = 2;
constexpr int N = 2048;
constexpr int QD = 1152;
constexpr int H = 16;
constexpr int D = 72;
constexpr int INNER = 1152;
constexpr int NKEEP = 819;            // int(2048*0.4)
constexpr int PSL = 32;               // power-iteration i-slices (matvec out)
constexpr int ILEN = N / PSL;         // 64
constexpr int DP = 80;                // padded head dim (5 blocks of 16)
constexpr int LSTR = 88;              // LDS row stride (bf16) for DP-wide tiles
constexpr int ASL = 16;               // argmax row-slices
constexpr int ACH = (NKEEP + ASL - 1) / ASL;  // 52
constexpr int ROWS = B * H * N;       // 65536
constexpr int X4 = (B * N * QD) / 4;  // 1179648 float4 units of x
constexpr size_t OSZ = (size_t)B * NKEEP * INNER;  // O-partial stride
constexpr int DSZ = B * H * NKEEP;                 // denom-partial stride
}

#define FINF __builtin_inff()
#define SCALE 0.11785113019775793f

typedef __attribute__((ext_vector_type(8))) __bf16 bf16x8;
typedef __attribute__((ext_vector_type(16))) float f32x16;
typedef __attribute__((ext_vector_type(8))) short short8;
typedef __attribute__((ext_vector_type(4))) short short4v;

__device__ __forceinline__ f32x16 mfma_bf16(bf16x8 a, bf16x8 b, f32x16 c) {
  return __builtin_amdgcn_mfma_f32_32x32x16_bf16(a, b, c, 0, 0, 0);
}
__device__ __forceinline__ short f2bf(float x) {
  unsigned u = __float_as_uint(x);
  unsigned r = (u + 0x7fffu + ((u >> 16) & 1u)) >> 16;
  return (short)r;
}
__device__ __forceinline__ float bf2f(short b) {
  return __uint_as_float(((unsigned)(unsigned short)b) << 16);
}

// ------- prep: vectorized x hi/lo split (float4) + QKV pad-column zeroing
__global__ __launch_bounds__(256) void k_prep(
    const float* __restrict__ X, short* __restrict__ Xh, short* __restrict__ Xl,
    short* __restrict__ qkv)
{
  int g = blockIdx.x * 256 + threadIdx.x;   // grid = X4 + 6*ROWS threads exactly
  if (g < X4) {
    float4 v = ((const float4*)X)[g];
    float vv[4] = {v.x, v.y, v.z, v.w};
    short4v h, l;
#pragma unroll
    for (int i = 0; i < 4; ++i) {
      short hb = f2bf(vv[i]);
      h[i] = hb;
      l[i] = f2bf(vv[i] - bf2f(hb));
    }
    *(short4v*)(void*)(Xh + (size_t)g * 4) = h;
    *(short4v*)(void*)(Xl + (size_t)g * 4) = l;
  } else {
    int t = g - X4;                         // 0 .. 6*ROWS-1
    int arr = t / ROWS, row = t - arr * ROWS;
    *(float4*)(void*)(qkv + (size_t)arr * ROWS * DP + (size_t)row * DP + 72) =
        make_float4(0.f, 0.f, 0.f, 0.f);
  }
}

// ---- W (KxN) -> WT hi/lo (N-major, split); z 0..2 -> Wq/Wk/Wv, z=3 -> Wo
__global__ __launch_bounds__(256) void k_wsplit4(
    const float* __restrict__ W0, const float* __restrict__ W1,
    const float* __restrict__ W2, const float* __restrict__ W3,
    short* __restrict__ WTh, short* __restrict__ WTl,
    short* __restrict__ WoTh, short* __restrict__ WoTl)
{
  __shared__ float tile[64][65];
  const int tid = threadIdx.x;
  const int k0 = blockIdx.y * 64, n0 = blockIdx.x * 64;
  const int z = blockIdx.z;
  const float* W = (z == 0) ? W0 : (z == 1) ? W1 : (z == 2) ? W2 : W3;
  short* outH = (z < 3) ? WTh + (size_t)z * QD * INNER : WoTh;
  short* outL = (z < 3) ? WTl + (size_t)z * QD * INNER : WoTl;
  {
    int r = tid >> 2, c0 = (tid & 3) * 16;
#pragma unroll
    for (int j = 0; j < 16; j += 4) {
      float4 v = *(const float4*)&W[(size_t)(k0 + r) * 1152 + n0 + c0 + j];
      tile[r][c0 + j] = v.x; tile[r][c0 + j + 1] = v.y;
      tile[r][c0 + j + 2] = v.z; tile[r][c0 + j + 3] = v.w;
    }
  }
  __syncthreads();
  for (int e = tid; e < 4096; e += 256) {
    int nr = e >> 6, kc = e & 63;
    float v = tile[kc][nr];
    short hb = f2bf(v);
    outH[(size_t)(n0 + nr) * 1152 + k0 + kc] = hb;
    outL[(size_t)(n0 + nr) * 1152 + k0 + kc] = f2bf(v - bf2f(hb));
  }
}

// ------------ fused QKV projection: A(4096x1152) @ [Wq|Wk|Wv]^T (3456 cols)
// PINNED round-12 body (131us, VGPR 60, MfmaUtil 33%): 128x128, 1D grid
// 864 = 8 XCD x 108 bijective swizzle, direct LDS staging, LK=40, (256,2).
// CLOSED after 6 structural attempts (see round 5/8/10/12/13 post-mortems).
__global__ __launch_bounds__(256, 2) void k_pgemm3(
    const short* __restrict__ Ah_g, const short* __restrict__ Al_g,
    const short* __restrict__ Bh_g, const short* __restrict__ Bl_g,
    short* __restrict__ QKV0)
{
  constexpr int LK = 40;   // 32 k + 8 pad
  __shared__ short AhS[128 * LK], AlS[128 * LK], BhS[128 * LK], BlS[128 * LK];
  const int tid = threadIdx.x;
  const int wv = tid >> 6, ln = tid & 63;
  const int col = ln & 31, hi = ln >> 5;
  const int wm = wv >> 1, wn = wv & 1;
  const int swz = (blockIdx.x & 7) * 108 + (blockIdx.x >> 3);
  const int m0 = (swz / 27) * 128, n0 = (swz % 27) * 128;

  f32x16 acc[2][2];
#pragma unroll
  for (int mi = 0; mi < 2; ++mi)
#pragma unroll
    for (int ni = 0; ni < 2; ++ni)
#pragma unroll
      for (int r = 0; r < 16; ++r) acc[mi][ni][r] = 0.f;

  for (int kt = 0; kt < 1152; kt += 32) {
    __syncthreads();
    for (int e = tid; e < 512; e += 256) {
      int r = e >> 2, c4 = e & 3;
      size_t sa = (size_t)(m0 + r) * 1152 + kt + c4 * 8;
      *(float4*)&AhS[r * LK + c4 * 8] = *(const float4*)(Ah_g + sa);
      *(float4*)&AlS[r * LK + c4 * 8] = *(const float4*)(Al_g + sa);
      size_t sb = (size_t)(n0 + r) * 1152 + kt + c4 * 8;
      *(float4*)&BhS[r * LK + c4 * 8] = *(const float4*)(Bh_g + sb);
      *(float4*)&BlS[r * LK + c4 * 8] = *(const float4*)(Bl_g + sb);
    }
    __syncthreads();
#pragma unroll
    for (int kc = 0; kc < 2; ++kc) {
      bf16x8 ah[2], al[2], bh[2], bl[2];
#pragma unroll
      for (int mi = 0; mi < 2; ++mi) {
        int r = wm * 64 + mi * 32 + col;
        ah[mi] = *(const bf16x8*)&AhS[r * LK + kc * 16 + hi * 8];
        al[mi] = *(const bf16x8*)&AlS[r * LK + kc * 16 + hi * 8];
      }
#pragma unroll
      for (int ni = 0; ni < 2; ++ni) {
        int r = wn * 64 + ni * 32 + col;
        bh[ni] = *(const bf16x8*)&BhS[r * LK + kc * 16 + hi * 8];
        bl[ni] = *(const bf16x8*)&BlS[r * LK + kc * 16 + hi * 8];
      }
#pragma unroll
      for (int mi = 0; mi < 2; ++mi)
#pragma unroll
        for (int ni = 0; ni < 2; ++ni) {
          acc[mi][ni] = mfma_bf16(ah[mi], bh[ni], acc[mi][ni]);
          acc[mi][ni] = mfma_bf16(ah[mi], bl[ni], acc[mi][ni]);
          acc[mi][ni] = mfma_bf16(al[mi], bh[ni], acc[mi][ni]);
        }
    }
  }
  const size_t S = (size_t)65536 * 80;   // elements per QKV hi (or lo) array
#pragma unroll
  for (int mi = 0; mi < 2; ++mi)
#pragma unroll
    for (int ni = 0; ni < 2; ++ni)
#pragma unroll
      for (int r = 0; r < 16; ++r) {
        int m = m0 + wm * 64 + mi * 32 + (r & 3) + 8 * (r >> 2) + 4 * hi;
        int c = n0 + wn * 64 + ni * 32 + col;
        int which = c / 1152, cm = c - which * 1152;
        int hh = cm / 72, dd = cm - hh * 72;
        int b = m >> 11, nn = m & 2047;
        size_t idx = (((size_t)(b * 16 + hh)) * 2048 + nn) * 80 + dd;
        float v = acc[mi][ni][r];
        short hb = f2bf(v);
        short* OH = QKV0 + (size_t)which * 2 * S;
        OH[idx] = hb;
        OH[S + idx] = f2bf(v - bf2f(hb));
      }
}

// ------------- softmax denominator PARTIALS via MFMA, q-tile 256, k-half
__global__ __launch_bounds__(256, 2) void k_stats3(
    const short* __restrict__ Qh, const short* __restrict__ Ql,
    const short* __restrict__ Kh, const short* __restrict__ Kl,
    float* __restrict__ ssum)
{
  __shared__ __align__(16) short kh[64 * LSTR];
  __shared__ __align__(16) short kl[64 * LSTR];
  const int tid = threadIdx.x;
  const int wv = tid >> 6, ln = tid & 63;
  const int col = ln & 31, hi = ln >> 5;
  const int hb = blockIdx.x & 31;
  const int rest = blockIdx.x >> 5;
  const int q0 = (rest & 7) * 256;
  const int ks = rest >> 3;               // 0 or 1
  const int h = hb >> 1, b = hb & 1;
  const size_t bhbase = (size_t)(b * H + h) * N * DP;
  const int kbeg = ks * (N / 2), kend = kbeg + N / 2;

  bf16x8 qfh[2][5], qfl[2][5];
#pragma unroll
  for (int mi = 0; mi < 2; ++mi) {
    const size_t rb = bhbase + (size_t)(q0 + wv * 64 + mi * 32 + col) * DP + hi * 8;
#pragma unroll
    for (int d = 0; d < 5; ++d) {
      qfh[mi][d] = *(const bf16x8*)(const void*)(Qh + rb + d * 16);
      qfl[mi][d] = *(const bf16x8*)(const void*)(Ql + rb + d * 16);
    }
  }
  float s[2][16];
#pragma unroll
  for (int mi = 0; mi < 2; ++mi)
#pragma unroll
    for (int r = 0; r < 16; ++r) s[mi][r] = 0.f;

  float4 rkh[3], rkl[3];
  auto LOADK = [&](int kt) {
#pragma unroll
    for (int ss = 0; ss < 3; ++ss) {
      int e = ss * 256 + tid;
      if (e < 640) {
        int r = e / 10, cc = e - r * 10;
        size_t sb = bhbase + (size_t)(kt + r) * DP + cc * 8;
        rkh[ss] = *(const float4*)(const void*)(Kh + sb);
        rkl[ss] = *(const float4*)(const void*)(Kl + sb);
      }
    }
  };
  auto STOREK = [&]() {
#pragma unroll
    for (int ss = 0; ss < 3; ++ss) {
      int e = ss * 256 + tid;
      if (e < 640) {
        int r = e / 10, cc = e - r * 10;
        *(float4*)(void*)(kh + r * LSTR + cc * 8) = rkh[ss];
        *(float4*)(void*)(kl + r * LSTR + cc * 8) = rkl[ss];
      }
    }
  };

  LOADK(kbeg);
  for (int kt = kbeg; kt < kend; kt += 64) {
    __syncthreads();
    STOREK();
    __syncthreads();
    if (kt + 64 < kend) LOADK(kt + 64);
    f32x16 z[2][2];
#pragma unroll
    for (int mi = 0; mi < 2; ++mi)
#pragma unroll
      for (int rn = 0; rn < 2; ++rn)
#pragma unroll
        for (int r = 0; r < 16; ++r) z[mi][rn][r] = 0.f;
#pragma unroll
    for (int d = 0; d < 5; ++d) {
      const int boff = d * 16 + hi * 8;
      bf16x8 bh0 = *(const bf16x8*)(const void*)(kh + col * LSTR + boff);
      bf16x8 bl0 = *(const bf16x8*)(const void*)(kl + col * LSTR + boff);
      bf16x8 bh1 = *(const bf16x8*)(const void*)(kh + (32 + col) * LSTR + boff);
      bf16x8 bl1 = *(const bf16x8*)(const void*)(kl + (32 + col) * LSTR + boff);
#pragma unroll
      for (int mi = 0; mi < 2; ++mi) {
        z[mi][0] = mfma_bf16(qfh[mi][d], bh0, z[mi][0]);
        z[mi][0] = mfma_bf16(qfh[mi][d], bl0, z[mi][0]);
        z[mi][0] = mfma_bf16(qfl[mi][d], bh0, z[mi][0]);
        z[mi][1] = mfma_bf16(qfh[mi][d], bh1, z[mi][1]);
        z[mi][1] = mfma_bf16(qfh[mi][d], bl1, z[mi][1]);
        z[mi][1] = mfma_bf16(qfl[mi][d], bh1, z[mi][1]);
      }
    }
#pragma unroll
    for (int mi = 0; mi < 2; ++mi)
#pragma unroll
      for (int r = 0; r < 16; ++r)
        s[mi][r] += __expf(z[mi][0][r] * SCALE) + __expf(z[mi][1][r] * SCALE);
  }
#pragma unroll
  for (int mi = 0; mi < 2; ++mi)
#pragma unroll
    for (int r = 0; r < 16; ++r) {
      float v = s[mi][r];
#pragma unroll
      for (int o = 1; o < 32; o <<= 1) v += __shfl_xor(v, o);
      if (col == 0) {
        int row = q0 + wv * 64 + mi * 32 + ((r & 3) + ((r >> 2) << 3) + (hi << 2));
        ssum[(size_t)ks * ROWS + (size_t)(b * H + h) * N + row] = v;
      }
    }
}

// ---- combine the 2 k-half partials into inv (fixed order, deterministic)
__global__ __launch_bounds__(256) void k_sinv(
    const float* __restrict__ ssum, float* __restrict__ inv_out)
{
  int g = blockIdx.x * 256 + threadIdx.x;
  if (g < ROWS) inv_out[g] = 1.0f / (ssum[g] + ssum[(size_t)ROWS + g]);
}

// --------------- head-averaged attention matrix, q-tile 256 x k-tile 64
__global__ __launch_bounds__(256, 2) void k_attn3(
    const short* __restrict__ Qh, const short* __restrict__ Ql,
    const short* __restrict__ Kh, const short* __restrict__ Kl,
    const float* __restrict__ inv_in, float* __restrict__ attn,
    float* __restrict__ part8)
{
  __shared__ __align__(16) short kh[64 * LSTR];
  __shared__ __align__(16) short kl[64 * LSTR];
  __shared__ float invs[256];
  __shared__ float colred[64][8];
  const int tid = threadIdx.x;
  const int wv = tid >> 6, ln = tid & 63;
  const int col = ln & 31, hi = ln >> 5;
  const int q0 = (blockIdx.x & 7) * 256;
  const int b = (blockIdx.x >> 3) & 1;
  const int k0 = (blockIdx.x >> 4) * 64;

  f32x16 pa[2][2];
#pragma unroll
  for (int mi = 0; mi < 2; ++mi)
#pragma unroll
    for (int rn = 0; rn < 2; ++rn)
#pragma unroll
      for (int r = 0; r < 16; ++r) pa[mi][rn][r] = 0.f;

  float4 rkh[3], rkl[3];
  float rin;
  auto LOADH = [&](int h) {
    const size_t hb = (size_t)(b * H + h) * N * DP;
#pragma unroll
    for (int ss = 0; ss < 3; ++ss) {
      int e = ss * 256 + tid;
      if (e < 640) {
        int r = e / 10, cc = e - r * 10;
        size_t sb = hb + (size_t)(k0 + r) * DP + cc * 8;
        rkh[ss] = *(const float4*)(const void*)(Kh + sb);
        rkl[ss] = *(const float4*)(const void*)(Kl + sb);
      }
    }
    rin = inv_in[(size_t)(b * H + h) * N + q0 + tid];
  };
  auto STOREH = [&]() {
#pragma unroll
    for (int ss = 0; ss < 3; ++ss) {
      int e = ss * 256 + tid;
      if (e < 640) {
        int r = e / 10, cc = e - r * 10;
        *(float4*)(void*)(kh + r * LSTR + cc * 8) = rkh[ss];
        *(float4*)(void*)(kl + r * LSTR + cc * 8) = rkl[ss];
      }
    }
    invs[tid] = rin;
  };

  LOADH(0);
  for (int h = 0; h < H; ++h) {
    __syncthreads();
    STOREH();
    __syncthreads();
    if (h + 1 < H) LOADH(h + 1);

    const size_t bhbase = (size_t)(b * H + h) * N * DP;
    f32x16 z[2][2];
#pragma unroll
    for (int mi = 0; mi < 2; ++mi)
#pragma unroll
      for (int rn = 0; rn < 2; ++rn)
#pragma unroll
        for (int r = 0; r < 16; ++r) z[mi][rn][r] = 0.f;

#pragma unroll
    for (int d = 0; d < 5; ++d) {
      const int boff = d * 16 + hi * 8;
      bf16x8 bh0 = *(const bf16x8*)(const void*)(kh + col * LSTR + boff);
      bf16x8 bl0 = *(const bf16x8*)(const void*)(kl + col * LSTR + boff);
      bf16x8 bh1 = *(const bf16x8*)(const void*)(kh + (32 + col) * LSTR + boff);
      bf16x8 bl1 = *(const bf16x8*)(const void*)(kl + (32 + col) * LSTR + boff);
      bf16x8 qh0 = *(const bf16x8*)(const void*)(Qh + bhbase + (size_t)(q0 + wv * 64 + col) * DP + boff);
      bf16x8 ql0 = *(const bf16x8*)(const void*)(Ql + bhbase + (size_t)(q0 + wv * 64 + col) * DP + boff);
      bf16x8 qh1 = *(const bf16x8*)(const void*)(Qh + bhbase + (size_t)(q0 + wv * 64 + 32 + col) * DP + boff);
      bf16x8 ql1 = *(const bf16x8*)(const void*)(Ql + bhbase + (size_t)(q0 + wv * 64 + 32 + col) * DP + boff);
      z[0][0] = mfma_bf16(qh0, bh0, z[0][0]);
      z[0][0] = mfma_bf16(qh0, bl0, z[0][0]);
      z[0][0] = mfma_bf16(ql0, bh0, z[0][0]);
      z[0][1] = mfma_bf16(qh0, bh1, z[0][1]);
      z[0][1] = mfma_bf16(qh0, bl1, z[0][1]);
      z[0][1] = mfma_bf16(ql0, bh1, z[0][1]);
      z[1][0] = mfma_bf16(qh1, bh0, z[1][0]);
      z[1][0] = mfma_bf16(qh1, bl0, z[1][0]);
      z[1][0] = mfma_bf16(ql1, bh0, z[1][0]);
      z[1][1] = mfma_bf16(qh1, bh1, z[1][1]);
      z[1][1] = mfma_bf16(qh1, bl1, z[1][1]);
      z[1][1] = mfma_bf16(ql1, bh1, z[1][1]);
    }
#pragma unroll
    for (int mi = 0; mi < 2; ++mi)
#pragma unroll
      for (int r = 0; r < 16; ++r) {
        const int rloc = wv * 64 + mi * 32 + (r & 3) + ((r >> 2) << 3) + (hi << 2);
        const float iv = invs[rloc];
        pa[mi][0][r] += __expf(z[mi][0][r] * SCALE) * iv;
        pa[mi][1][r] += __expf(z[mi][1][r] * SCALE) * iv;
      }
  }
  const float invH = 1.0f / H;
#pragma unroll
  for (int mi = 0; mi < 2; ++mi)
#pragma unroll
    for (int r = 0; r < 16; ++r) {
      const int row = q0 + wv * 64 + mi * 32 + (r & 3) + ((r >> 2) << 3) + (hi << 2);
      attn[((size_t)b * N + row) * N + k0 + col] = pa[mi][0][r] * invH;
      attn[((size_t)b * N + row) * N + k0 + 32 + col] = pa[mi][1][r] * invH;
    }
  // ---- first matvec partials: per-column sum over this block's 256 rows
  __syncthreads();
#pragma unroll
  for (int rn = 0; rn < 2; ++rn) {
    float s = 0.f;
#pragma unroll
    for (int mi = 0; mi < 2; ++mi)
#pragma unroll
      for (int r = 0; r < 16; ++r) s += pa[mi][rn][r];
    colred[rn * 32 + col][wv * 2 + hi] = s * invH;
  }
  __syncthreads();
  if (tid < 64) {
    float s = 0.f;
#pragma unroll
    for (int u = 0; u < 8; ++u) s += colred[tid][u];
    part8[(size_t)(q0 >> 8) * (B * N) + b * N + k0 + tid] = s * (1.0f / N);
  }
}

// matvec step: reduce nin slices of partial_in for this block's 64 rows, matvec
// 4-way split accumulator breaks the serial FMA dependency chain.
__global__ __launch_bounds__(256) void k_powfused(
    const float* __restrict__ attn, const float* __restrict__ partial_in,
    float* __restrict__ partial_out, int nin)
{
  __shared__ float red[4][64];
  __shared__ float ds[64];
  const int tid = threadIdx.x;
  const int g = blockIdx.x * 256 + tid;
  const int sy = blockIdx.y;
  const int b = g / N, j = g % N;
  const int i0 = sy * ILEN;
  {
    int i = tid & 63, sgrp = tid >> 6;
    const int per = nin >> 2;
    const float* p = partial_in + (size_t)(b * N + i0 + i);
    float s8 = 0.f;
    for (int k = 0; k < per; ++k) s8 += p[(size_t)(sgrp * per + k) * (B * N)];
    red[sgrp][i] = s8;
  }
  __syncthreads();
  if (tid < 64) ds[tid] = red[0][tid] + red[1][tid] + red[2][tid] + red[3][tid];
  __syncthreads();
  const float* ab = attn + (size_t)b * N * N;
  float s0 = 0.f, s1 = 0.f, s2 = 0.f, s3 = 0.f;
  for (int i = 0; i < ILEN; i += 4) {
    s0 += ds[i + 0] * ab[(size_t)(i0 + i + 0) * N + j];
    s1 += ds[i + 1] * ab[(size_t)(i0 + i + 1) * N + j];
    s2 += ds[i + 2] * ab[(size_t)(i0 + i + 2) * N + j];
    s3 += ds[i + 3] * ab[(size_t)(i0 + i + 3) * N + j];
  }
  partial_out[(size_t)sy * (B * N) + g] = (s0 + s1) + (s2 + s3);
}

// ------- top-k partition (bitonic sort); input = 32-slice partial vector
__global__ __launch_bounds__(1024) void k_partition(
    const float* __restrict__ partial, int* __restrict__ sorted_imp,
    int* __restrict__ keepflag, int* __restrict__ s_map)
{
  __shared__ float v[N];
  __shared__ int   id[N];
  __shared__ int   kf[N];
  __shared__ int   ps[N];
  const int tid = threadIdx.x;
  const int b = blockIdx.x;
  for (int i = tid; i < N; i += 1024) {
    float s = 0.f;
    const float* p = partial + (size_t)(b * N + i);
    for (int sy = 0; sy < PSL; ++sy) s += p[(size_t)sy * (B * N)];
    v[i] = s; id[i] = i;
  }
  for (int k = 2; k <= N; k <<= 1) {
    for (int j = k >> 1; j > 0; j >>= 1) {
      __syncthreads();
      for (int i = tid; i < N; i += 1024) {
        int ixj = i ^ j;
        if (ixj > i) {
          bool up = ((i & k) == 0);
          float va = v[i], vb = v[ixj];
          int ia = id[i], ib = id[ixj];
          bool b_before_a = (vb > va) || (vb == va && ib < ia);
          if (b_before_a == up) { v[i] = vb; v[ixj] = va; id[i] = ib; id[ixj] = ia; }
        }
      }
    }
  }
  __syncthreads();
  for (int i = tid; i < N; i += 1024) kf[id[i]] = (i < NKEEP) ? 1 : 0;
  __syncthreads();
  for (int i = tid; i < N; i += 1024) ps[i] = kf[i];
  for (int off = 1; off < N; off <<= 1) {
    __syncthreads();
    int t0 = (tid >= off) ? ps[tid - off] : 0;
    int i1 = tid + 1024;
    int t1 = ps[i1 - off];
    __syncthreads();
    ps[tid] += t0;
    ps[i1] += t1;
  }
  __syncthreads();
  for (int i = tid; i < N; i += 1024) {
    int excl = ps[i] - kf[i];
    keepflag[b * N + i] = kf[i];
    if (kf[i]) { sorted_imp[b * NKEEP + excl] = i; s_map[b * N + i] = excl; }
  }
}

// --------------- per-column argmax over kept rows, sliced (16x parallelism)
__global__ __launch_bounds__(256) void k_argmax_part(
    const float* __restrict__ attn, const int* __restrict__ sorted_imp,
    float* __restrict__ pval, int* __restrict__ pidx)
{
  __shared__ int imp_s[ACH];
  const int tid = threadIdx.x;
  const int g = blockIdx.x * 256 + tid;
  const int s = blockIdx.y;
  const int b = g / N, n = g % N;
  const int k0 = s * ACH;
  const int k1 = (k0 + ACH < NKEEP) ? k0 + ACH : NKEEP;
  const int cnt = k1 - k0;
  for (int i = tid; i < cnt; i += 256) imp_s[i] = sorted_imp[b * NKEEP + k0 + i];
  __syncthreads();
  const float* ab = attn + (size_t)b * N * N;
  float best = -FINF; int bi = k0;
  for (int k = 0; k < cnt; ++k) {
    float val = ab[(size_t)imp_s[k] * N + n];
    if (val > best) { best = val; bi = k0 + k; }   // strict >: first max
  }
  pval[(size_t)s * (B * N) + g] = best;
  pidx[(size_t)s * (B * N) + g] = bi;
}

// combine ascending: strict > keeps earliest k on ties (jnp.argmax semantics)
__global__ __launch_bounds__(256) void k_argmax_comb(
    const float* __restrict__ pval, const int* __restrict__ pidx,
    const int* __restrict__ keepflag, int* __restrict__ s_map)
{
  int g = blockIdx.x * 256 + threadIdx.x;
  if (g >= B * N) return;
  float best = -FINF; int bi = 0;
#pragma unroll
  for (int s = 0; s < ASL; ++s) {
    float v = pval[(size_t)s * (B * N) + g];
    if (v > best) { best = v; bi = pidx[(size_t)s * (B * N) + g]; }
  }
  if (!keepflag[g]) s_map[g] = bi;
}

// -------- fused reduced attention, KV-SPLIT: gathered QK^T + exp + PV (MFMA)
// grid (7, 16, 4): z = b + 2*ks; ks=0 -> k-tiles 0..6 (k<448), ks=1 -> 7..12.
// Writes UNNORMALIZED O-partials + denominator partials; k_rcomb combines.
// 448 blocks (was 224) -> full CU coverage, latency-heavy gathers overlapped.
__global__ __launch_bounds__(256, 2) void k_rfused(
    const short* __restrict__ Qh, const short* __restrict__ Ql,
    const short* __restrict__ Kh, const short* __restrict__ Kl,
    const short* __restrict__ Vh, const int* __restrict__ sorted_imp,
    float* __restrict__ Opart, float* __restrict__ dpart)
{
  constexpr int LK = 88;
  constexpr int VTS = 72;
  __shared__ __align__(16) short KhS[64 * LK];
  __shared__ __align__(16) short KlS[64 * LK];
  __shared__ __align__(16) short VhS[64 * LK];
  __shared__ __align__(16) short VT[72 * VTS];
  __shared__ int imp[NKEEP];
  const int tid = threadIdx.x;
  const int wv = tid >> 6, ln = tid & 63;
  const int col = ln & 31, hi = ln >> 5;
  const int b = blockIdx.z & 1, ks = blockIdx.z >> 1;
  const int h = blockIdx.y, q0 = blockIdx.x * 128;
  const int kbeg = ks ? 448 : 0, kend = ks ? 832 : 448;
  const size_t bh80 = (size_t)(b * H + h) * N * DP;
  for (int i = tid; i < NKEEP; i += 256) imp[i] = sorted_imp[b * NKEEP + i];
  __syncthreads();
  int qr = q0 + wv * 32 + col;
  int qi = imp[qr < NKEEP ? qr : NKEEP - 1];
  bf16x8 qfh[5], qfl[5];
  {
    const size_t qb = bh80 + (size_t)qi * DP + hi * 8;
#pragma unroll
    for (int d = 0; d < 5; ++d) {
      qfh[d] = *(const bf16x8*)(const void*)(Qh + qb + d * 16);
      qfl[d] = *(const bf16x8*)(const void*)(Ql + qb + d * 16);
    }
  }
  float denom = 0.f;
  f32x16 oacc[3];
#pragma unroll
  for (int nc = 0; nc < 3; ++nc)
#pragma unroll
    for (int r = 0; r < 16; ++r) oacc[nc][r] = 0.f;

  for (int kt = kbeg; kt < kend; kt += 64) {
    for (int e = tid; e < 640; e += 256) {
      int r = e / 10, cc = e - r * 10;
      int kv = kt + r;
      float4 vkh, vkl, vvh;
      if (kv < NKEEP) {
        size_t sb = bh80 + (size_t)imp[kv] * DP + cc * 8;
        vkh = *(const float4*)(const void*)(Kh + sb);
        vkl = *(const float4*)(const void*)(Kl + sb);
        vvh = *(const float4*)(const void*)(Vh + sb);
      } else {
        vkh = make_float4(0.f, 0.f, 0.f, 0.f); vkl = vkh; vvh = vkh;
      }
      *(float4*)(void*)&KhS[r * LK + cc * 8] = vkh;
      *(float4*)(void*)&KlS[r * LK + cc * 8] = vkl;
      *(float4*)(void*)&VhS[r * LK + cc * 8] = vvh;
    }
    __syncthreads();
    f32x16 z[2];
#pragma unroll
    for (int rn = 0; rn < 2; ++rn)
#pragma unroll
      for (int r = 0; r < 16; ++r) z[rn][r] = 0.f;
#pragma unroll
    for (int d = 0; d < 5; ++d) {
      const int boff = d * 16 + hi * 8;
#pragma unroll
      for (int rn = 0; rn < 2; ++rn) {
        bf16x8 kfh = *(const bf16x8*)(const void*)(KhS + (rn * 32 + col) * LK + boff);
        bf16x8 kfl = *(const bf16x8*)(const void*)(KlS + (rn * 32 + col) * LK + boff);
        z[rn] = mfma_bf16(kfh, qfh[d], z[rn]);
        z[rn] = mfma_bf16(kfh, qfl[d], z[rn]);
        z[rn] = mfma_bf16(kfl, qfh[d], z[rn]);
      }
    }
    for (int e = tid; e < 576; e += 256) {
      int dd = e % 72, k8 = e / 72;
      short8 t;
#pragma unroll
      for (int j = 0; j < 8; ++j) t[j] = VhS[(k8 * 8 + j) * LK + dd];
      *(short8*)(void*)&VT[dd * VTS + k8 * 8] = t;
    }
    const bool full = (kt + 64 <= NKEEP);
#pragma unroll
    for (int rn = 0; rn < 2; ++rn) {
      int kvb = kt + rn * 32 + 4 * hi;
#pragma unroll
      for (int r = 0; r < 16; ++r) {
        float pe = __expf(z[rn][r] * SCALE);
        if (!full) {
          int kv = kvb + (r & 3) + 8 * (r >> 2);
          pe = (kv < NKEEP) ? pe : 0.f;
        }
        z[rn][r] = pe;
        denom += pe;
      }
    }
    __syncthreads();
#pragma unroll
    for (int rn = 0; rn < 2; ++rn) {
#pragma unroll
      for (int kc = 0; kc < 2; ++kc) {
        unsigned p0, p1, p2, p3;
        asm("v_cvt_pk_bf16_f32 %0, %1, %2" : "=v"(p0) : "v"(z[rn][8 * kc + 0]), "v"(z[rn][8 * kc + 1]));
        asm("v_cvt_pk_bf16_f32 %0, %1, %2" : "=v"(p1) : "v"(z[rn][8 * kc + 2]), "v"(z[rn][8 * kc + 3]));
        asm("v_cvt_pk_bf16_f32 %0, %1, %2" : "=v"(p2) : "v"(z[rn][8 * kc + 4]), "v"(z[rn][8 * kc + 5]));
        asm("v_cvt_pk_bf16_f32 %0, %1, %2" : "=v"(p3) : "v"(z[rn][8 * kc + 6]), "v"(z[rn][8 * kc + 7]));
        unsigned othA = hi ? p0 : p2, othB = hi ? p1 : p3;
        unsigned swA = (unsigned)__shfl_xor((int)othA, 32);
        unsigned swB = (unsigned)__shfl_xor((int)othB, 32);
        union { unsigned u[4]; bf16x8 v; } pf;
        pf.u[0] = hi ? swA : p0; pf.u[1] = hi ? swB : p1;
        pf.u[2] = hi ? p2 : swA; pf.u[3] = hi ? p3 : swB;
        const int kb = rn * 32 + kc * 16 + hi * 8;
#pragma unroll
        for (int nc = 0; nc < 3; ++nc) {
          int dr = nc * 32 + col; if (dr > 71) dr = 71;
          bf16x8 vf = *(const bf16x8*)(const void*)(VT + dr * VTS + kb);
          oacc[nc] = mfma_bf16(pf.v, vf, oacc[nc]);
        }
      }
    }
  }
  // unnormalized O-partial write (no cross-lane needed)
#pragma unroll
  for (int r = 0; r < 16; ++r) {
    int cr = (r & 3) + 8 * (r >> 2) + 4 * hi;
    int q = q0 + wv * 32 + cr;
    if (q < NKEEP) {
#pragma unroll
      for (int nc = 0; nc < 3; ++nc) {
        int dd = nc * 32 + col;
        if (dd < 72)
          Opart[(size_t)ks * OSZ + ((size_t)b * NKEEP + q) * 1152 + h * 72 + dd] =
              oacc[nc][r];
      }
    }
  }
  // denominator partial: lanes 0..31 hold the full per-q-col sum after swap-add
  denom += __shfl_xor(denom, 32);
  if (hi == 0) {
    int q = q0 + wv * 32 + col;
    if (q < NKEEP)
      dpart[ks * DSZ + (b * H + h) * NKEEP + q] = denom;
  }
}

// ---- combine KV-half partials: Y = (O0+O1) * 1/(d0+d1), bf16 hi/lo split
__global__ __launch_bounds__(256) void k_rcomb(
    const float* __restrict__ Opart, const float* __restrict__ dpart,
    short* __restrict__ Yh, short* __restrict__ Yl)
{
  size_t g = (size_t)blockIdx.x * 256 + threadIdx.x;   // grid exact: OSZ/256
  int c = (int)(g % 1152);
  int q = (int)((g / 1152) % NKEEP);
  int b = (int)(g / ((size_t)NKEEP * 1152));
  int h = c / 72;
  float o = Opart[g] + Opart[OSZ + g];
  float d = dpart[(b * H + h) * NKEEP + q] + dpart[DSZ + (b * H + h) * NKEEP + q];
  float v = o * (1.0f / d);
  short hb = f2bf(v);
  Yh[g] = hb;
  Yl[g] = f2bf(v - bf2f(hb));
}

// ---- output projection, SCATTERED epilogue: writes kept rows directly into
// out[b][sorted_imp[m]] (rows are 4.6KB contiguous -> coalescing preserved)
__global__ __launch_bounds__(256, 2) void k_ogemm(
    const short* __restrict__ Ah_g, const short* __restrict__ Al_g,
    const short* __restrict__ Bh_g, const short* __restrict__ Bl_g,
    const int* __restrict__ sorted_imp,
    float* __restrict__ OutF, const float* __restrict__ bias,
    int Mtot)
{
  constexpr int LK = 40;
  __shared__ short AhS[64 * LK], AlS[64 * LK], BhS[64 * LK], BlS[64 * LK];
  const int tid = threadIdx.x;
  const int wv = tid >> 6, ln = tid & 63;
  const int col = ln & 31, hi = ln >> 5;
  const int wm = wv >> 1, wn = wv & 1;
  const int m0 = blockIdx.y * 64, n0 = blockIdx.x * 64;
  f32x16 acc;
#pragma unroll
  for (int r = 0; r < 16; ++r) acc[r] = 0.f;

  for (int kt = 0; kt < 1152; kt += 32) {
    __syncthreads();
    {
      int e = tid;
      int r = e >> 2, c4 = e & 3;
      int ra = m0 + r; if (ra >= Mtot) ra = Mtot - 1;
      size_t sa = (size_t)ra * 1152 + kt + c4 * 8;
      *(float4*)&AhS[r * LK + c4 * 8] = *(const float4*)(Ah_g + sa);
      *(float4*)&AlS[r * LK + c4 * 8] = *(const float4*)(Al_g + sa);
      size_t sb = (size_t)(n0 + r) * 1152 + kt + c4 * 8;
      *(float4*)&BhS[r * LK + c4 * 8] = *(const float4*)(Bh_g + sb);
      *(float4*)&BlS[r * LK + c4 * 8] = *(const float4*)(Bl_g + sb);
    }
    __syncthreads();
#pragma unroll
    for (int kc = 0; kc < 2; ++kc) {
      int ra = wm * 32 + col;
      int rb = wn * 32 + col;
      bf16x8 ah = *(const bf16x8*)&AhS[ra * LK + kc * 16 + hi * 8];
      bf16x8 al = *(const bf16x8*)&AlS[ra * LK + kc * 16 + hi * 8];
      bf16x8 bh = *(const bf16x8*)&BhS[rb * LK + kc * 16 + hi * 8];
      bf16x8 bl = *(const bf16x8*)&BlS[rb * LK + kc * 16 + hi * 8];
      acc = mfma_bf16(ah, bh, acc);
      acc = mfma_bf16(ah, bl, acc);
      acc = mfma_bf16(al, bh, acc);
    }
  }
#pragma unroll
  for (int r = 0; r < 16; ++r) {
    int m = m0 + wm * 32 + (r & 3) + 8 * (r >> 2) + 4 * hi;
    int c = n0 + wn * 32 + col;
    if (m < Mtot) {
      int b = m / NKEEP, mm = m - b * NKEEP;
      int orig = sorted_imp[b * NKEEP + mm];
      OutF[((size_t)b * N + orig) * 1152 + c] = acc[r] + bias[c];
    }
  }
}

// ---- pruned-row copy: out[b][n] = out[b][sorted_imp[s_map[n]]] for !kept
__global__ __launch_bounds__(256) void k_prune(
    const int* __restrict__ keepflag, const int* __restrict__ sorted_imp,
    const int* __restrict__ s_map, float* __restrict__ out)
{
  size_t g = (size_t)blockIdx.x * 256 + threadIdx.x;
  if (g >= (size_t)B * N * QD) return;
  int c = (int)(g % QD);
  int n_ = (int)((g / QD) % N);
  int b = (int)(g / ((size_t)N * QD));
  if (keepflag[b * N + n_]) return;
  int src = sorted_imp[b * NKEEP + s_map[b * N + n_]];
  out[g] = out[((size_t)b * N + src) * QD + c];
}

// ---------------------------------------------------------------- launch
extern "C" void kernel_launch(void* const* d_in, const int* in_sizes, int n_in,
                              void* d_out, int out_size, void* d_ws, size_t ws_size,
                              hipStream_t stream)
{
  const float* x  = (const float*)d_in[0];
  const float* Wq = (const float*)d_in[1];
  const float* Wk = (const float*)d_in[2];
  const float* Wv = (const float*)d_in[3];
  const float* Wo = (const float*)d_in[4];
  const float* bo = (const float*)d_in[5];
  float* out = (float*)d_out;

  char* ws = (char*)d_ws;
  size_t off = 0;
  auto alloc = [&](size_t bytes) -> void* {
    void* p = ws + off;
    off = (off + bytes + 255) & ~(size_t)255;
    return p;
  };
  const size_t XEL = (size_t)B * N * QD;    // 4718592
  const size_t WEL = (size_t)QD * INNER;    // 1327104
  short* xh   = (short*)alloc(sizeof(short) * XEL);
  short* xl   = (short*)alloc(sizeof(short) * XEL);
  short* WTh  = (short*)alloc(sizeof(short) * WEL * 3);   // [Wq|Wk|Wv]^T hi
  short* WTl  = (short*)alloc(sizeof(short) * WEL * 3);   // lo
  short* WoTh = (short*)alloc(sizeof(short) * WEL);
  short* WoTl = (short*)alloc(sizeof(short) * WEL);
  short* Qhb  = (short*)alloc(sizeof(short) * (size_t)ROWS * DP);
  short* Qlb  = (short*)alloc(sizeof(short) * (size_t)ROWS * DP);
  short* Khb  = (short*)alloc(sizeof(short) * (size_t)ROWS * DP);
  short* Klb  = (short*)alloc(sizeof(short) * (size_t)ROWS * DP);
  short* Vhb  = (short*)alloc(sizeof(short) * (size_t)ROWS * DP);
  short* Vlb  = (short*)alloc(sizeof(short) * (size_t)ROWS * DP);
  float* attn = (float*)alloc(sizeof(float) * (size_t)B * N * N);
  float* ssum = (float*)alloc(sizeof(float) * 2 * (size_t)ROWS);
  float* inv  = (float*)alloc(sizeof(float) * (size_t)ROWS);
  float* partA = (float*)alloc(sizeof(float) * PSL * B * N);
  float* partB = (float*)alloc(sizeof(float) * PSL * B * N);
  float* dpart = (float*)alloc(sizeof(float) * 2 * DSZ);
  int* sorted_imp = (int*)alloc(sizeof(int) * B * NKEEP);
  int* keepflag   = (int*)alloc(sizeof(int) * B * N);
  int* s_map      = (int*)alloc(sizeof(int) * B * N);
  float* pval     = (float*)alloc(sizeof(float) * ASL * B * N);
  int*   pidx     = (int*)alloc(sizeof(int) * ASL * B * N);
  (void)Vlb;
  // aliases into dead regions:
  short* Yh = xh;                      // bf16 hi of reduced-attn output
  short* Yl = xh + (size_t)B * NKEEP * INNER;
  float* Opart = attn;                 // 2 x 7.55MB O-partials in dead attn

  dim3 blk(256);

  // prep: vectorized x split + QKV pad zeroing (exact grid), W splits (1 launch)
  k_prep<<<dim3((X4 + 6 * ROWS) / 256), blk, 0, stream>>>(x, xh, xl, Qhb);
  k_wsplit4<<<dim3(QD / 64, QD / 64, 4), blk, 0, stream>>>(
      Wq, Wk, Wv, Wo, WTh, WTl, WoTh, WoTl);

  // fused QKV projection (1D grid 864, XCD-swizzled, direct staging — pinned)
  k_pgemm3<<<dim3(864), blk, 0, stream>>>(xh, xl, WTh, WTl, Qhb);

  // full attention: denominator partials (k-split, 512 blocks) + combine +
  // head-averaged matrix (+ first matvec into partB)
  k_stats3<<<dim3(512), blk, 0, stream>>>(Qhb, Qlb, Khb, Klb, ssum);
  k_sinv<<<dim3(ROWS / 256), blk, 0, stream>>>(ssum, inv);
  k_attn3<<<dim3(512), blk, 0, stream>>>(Qhb, Qlb, Khb, Klb, inv, attn, partB);

  // remaining 4 power-iteration matvecs; partition reduces the final 32 slices
  k_powfused<<<dim3(B * N / 256, PSL), blk, 0, stream>>>(attn, partB, partA, 8);
  k_powfused<<<dim3(B * N / 256, PSL), blk, 0, stream>>>(attn, partA, partB, 32);
  k_powfused<<<dim3(B * N / 256, PSL), blk, 0, stream>>>(attn, partB, partA, 32);
  k_powfused<<<dim3(B * N / 256, PSL), blk, 0, stream>>>(attn, partA, partB, 32);

  // top-k partition (folds final 32-slice reduce) + sliced per-column argmax
  k_partition<<<dim3(B), dim3(1024), 0, stream>>>(partB, sorted_imp, keepflag, s_map);
  k_argmax_part<<<dim3(B * N / 256, ASL), blk, 0, stream>>>(attn, sorted_imp, pval, pidx);
  k_argmax_comb<<<dim3(B * N / 256), blk, 0, stream>>>(pval, pidx, keepflag, s_map);

  // fused reduced attention, KV-split over 448 blocks (attn is dead ->
  // Opart aliases it), then combine into Yh/Yl
  k_rfused<<<dim3((NKEEP + 127) / 128, H, 2 * B), blk, 0, stream>>>(
      Qhb, Qlb, Khb, Klb, Vhb, sorted_imp, Opart, dpart);
  k_rcomb<<<dim3((int)(OSZ / 256)), blk, 0, stream>>>(Opart, dpart, Yh, Yl);

  // output projection scatter-writes kept rows into out; prune copies the rest
  k_ogemm<<<dim3(QD / 64, (B * NKEEP + 63) / 64), blk, 0, stream>>>(
      Yh, Yl, WoTh, WoTl, sorted_imp, out, bo, B * NKEEP);
  k_prune<<<dim3((int)(((size_t)B * N * QD + 255) / 256)), blk, 0, stream>>>(
      keepflag, sorted_imp, s_map, out);
}

// Round 19
// 492.073 us; speedup vs baseline: 1.0227x; 1.0039x over previous
//
#include <hip/hip_runtime.h>

namespace {
constexpr int B = 2;
constexpr int N = 2048;
constexpr int QD = 1152;
constexpr int H = 16;
constexpr int D = 72;
constexpr int INNER = 1152;
constexpr int NKEEP = 819;            // int(2048*0.4)
constexpr int NPRUNE = N - NKEEP;     // 1229
constexpr int PSL = 32;               // power-iteration i-slices (matvec out)
constexpr int ILEN = N / PSL;         // 64
constexpr int DP = 80;                // padded head dim (5 blocks of 16)
constexpr int LSTR = 88;              // LDS row stride (bf16) for DP-wide tiles
constexpr int ASL = 16;               // argmax row-slices
constexpr int ACH = (NKEEP + ASL - 1) / ASL;  // 52
constexpr int ROWS = B * H * N;       // 65536
constexpr int X4 = (B * N * QD) / 4;  // 1179648 float4 units of x
constexpr size_t OSZ = (size_t)B * NKEEP * INNER;  // O-partial stride
constexpr int DSZ = B * H * NKEEP;                 // denom-partial stride
}

#define FINF __builtin_inff()
#define SCALE 0.11785113019775793f

typedef __attribute__((ext_vector_type(8))) __bf16 bf16x8;
typedef __attribute__((ext_vector_type(16))) float f32x16;
typedef __attribute__((ext_vector_type(8))) short short8;
typedef __attribute__((ext_vector_type(4))) short short4v;

__device__ __forceinline__ f32x16 mfma_bf16(bf16x8 a, bf16x8 b, f32x16 c) {
  return __builtin_amdgcn_mfma_f32_32x32x16_bf16(a, b, c, 0, 0, 0);
}
__device__ __forceinline__ short f2bf(float x) {
  unsigned u = __float_as_uint(x);
  unsigned r = (u + 0x7fffu + ((u >> 16) & 1u)) >> 16;
  return (short)r;
}
__device__ __forceinline__ float bf2f(short b) {
  return __uint_as_float(((unsigned)(unsigned short)b) << 16);
}

// ------- prep: vectorized x hi/lo split (float4) + QKV pad-column zeroing
__global__ __launch_bounds__(256) void k_prep(
    const float* __restrict__ X, short* __restrict__ Xh, short* __restrict__ Xl,
    short* __restrict__ qkv)
{
  int g = blockIdx.x * 256 + threadIdx.x;   // grid = X4 + 6*ROWS threads exactly
  if (g < X4) {
    float4 v = ((const float4*)X)[g];
    float vv[4] = {v.x, v.y, v.z, v.w};
    short4v h, l;
#pragma unroll
    for (int i = 0; i < 4; ++i) {
      short hb = f2bf(vv[i]);
      h[i] = hb;
      l[i] = f2bf(vv[i] - bf2f(hb));
    }
    *(short4v*)(void*)(Xh + (size_t)g * 4) = h;
    *(short4v*)(void*)(Xl + (size_t)g * 4) = l;
  } else {
    int t = g - X4;                         // 0 .. 6*ROWS-1
    int arr = t / ROWS, row = t - arr * ROWS;
    *(float4*)(void*)(qkv + (size_t)arr * ROWS * DP + (size_t)row * DP + 72) =
        make_float4(0.f, 0.f, 0.f, 0.f);
  }
}

// ---- W (KxN) -> WT hi/lo (N-major, split); z 0..2 -> Wq/Wk/Wv, z=3 -> Wo
__global__ __launch_bounds__(256) void k_wsplit4(
    const float* __restrict__ W0, const float* __restrict__ W1,
    const float* __restrict__ W2, const float* __restrict__ W3,
    short* __restrict__ WTh, short* __restrict__ WTl,
    short* __restrict__ WoTh, short* __restrict__ WoTl)
{
  __shared__ float tile[64][65];
  const int tid = threadIdx.x;
  const int k0 = blockIdx.y * 64, n0 = blockIdx.x * 64;
  const int z = blockIdx.z;
  const float* W = (z == 0) ? W0 : (z == 1) ? W1 : (z == 2) ? W2 : W3;
  short* outH = (z < 3) ? WTh + (size_t)z * QD * INNER : WoTh;
  short* outL = (z < 3) ? WTl + (size_t)z * QD * INNER : WoTl;
  {
    int r = tid >> 2, c0 = (tid & 3) * 16;
#pragma unroll
    for (int j = 0; j < 16; j += 4) {
      float4 v = *(const float4*)&W[(size_t)(k0 + r) * 1152 + n0 + c0 + j];
      tile[r][c0 + j] = v.x; tile[r][c0 + j + 1] = v.y;
      tile[r][c0 + j + 2] = v.z; tile[r][c0 + j + 3] = v.w;
    }
  }
  __syncthreads();
  for (int e = tid; e < 4096; e += 256) {
    int nr = e >> 6, kc = e & 63;
    float v = tile[kc][nr];
    short hb = f2bf(v);
    outH[(size_t)(n0 + nr) * 1152 + k0 + kc] = hb;
    outL[(size_t)(n0 + nr) * 1152 + k0 + kc] = f2bf(v - bf2f(hb));
  }
}

// ------------ fused QKV projection: A(4096x1152) @ [Wq|Wk|Wv]^T (3456 cols)
// PINNED round-12 body (131us, VGPR 60, MfmaUtil 33%): 128x128, 1D grid
// 864 = 8 XCD x 108 bijective swizzle, direct LDS staging, LK=40, (256,2).
// CLOSED after 6 structural attempts (see round 5/8/10/12/13 post-mortems).
__global__ __launch_bounds__(256, 2) void k_pgemm3(
    const short* __restrict__ Ah_g, const short* __restrict__ Al_g,
    const short* __restrict__ Bh_g, const short* __restrict__ Bl_g,
    short* __restrict__ QKV0)
{
  constexpr int LK = 40;   // 32 k + 8 pad
  __shared__ short AhS[128 * LK], AlS[128 * LK], BhS[128 * LK], BlS[128 * LK];
  const int tid = threadIdx.x;
  const int wv = tid >> 6, ln = tid & 63;
  const int col = ln & 31, hi = ln >> 5;
  const int wm = wv >> 1, wn = wv & 1;
  const int swz = (blockIdx.x & 7) * 108 + (blockIdx.x >> 3);
  const int m0 = (swz / 27) * 128, n0 = (swz % 27) * 128;

  f32x16 acc[2][2];
#pragma unroll
  for (int mi = 0; mi < 2; ++mi)
#pragma unroll
    for (int ni = 0; ni < 2; ++ni)
#pragma unroll
      for (int r = 0; r < 16; ++r) acc[mi][ni][r] = 0.f;

  for (int kt = 0; kt < 1152; kt += 32) {
    __syncthreads();
    for (int e = tid; e < 512; e += 256) {
      int r = e >> 2, c4 = e & 3;
      size_t sa = (size_t)(m0 + r) * 1152 + kt + c4 * 8;
      *(float4*)&AhS[r * LK + c4 * 8] = *(const float4*)(Ah_g + sa);
      *(float4*)&AlS[r * LK + c4 * 8] = *(const float4*)(Al_g + sa);
      size_t sb = (size_t)(n0 + r) * 1152 + kt + c4 * 8;
      *(float4*)&BhS[r * LK + c4 * 8] = *(const float4*)(Bh_g + sb);
      *(float4*)&BlS[r * LK + c4 * 8] = *(const float4*)(Bl_g + sb);
    }
    __syncthreads();
#pragma unroll
    for (int kc = 0; kc < 2; ++kc) {
      bf16x8 ah[2], al[2], bh[2], bl[2];
#pragma unroll
      for (int mi = 0; mi < 2; ++mi) {
        int r = wm * 64 + mi * 32 + col;
        ah[mi] = *(const bf16x8*)&AhS[r * LK + kc * 16 + hi * 8];
        al[mi] = *(const bf16x8*)&AlS[r * LK + kc * 16 + hi * 8];
      }
#pragma unroll
      for (int ni = 0; ni < 2; ++ni) {
        int r = wn * 64 + ni * 32 + col;
        bh[ni] = *(const bf16x8*)&BhS[r * LK + kc * 16 + hi * 8];
        bl[ni] = *(const bf16x8*)&BlS[r * LK + kc * 16 + hi * 8];
      }
#pragma unroll
      for (int mi = 0; mi < 2; ++mi)
#pragma unroll
        for (int ni = 0; ni < 2; ++ni) {
          acc[mi][ni] = mfma_bf16(ah[mi], bh[ni], acc[mi][ni]);
          acc[mi][ni] = mfma_bf16(ah[mi], bl[ni], acc[mi][ni]);
          acc[mi][ni] = mfma_bf16(al[mi], bh[ni], acc[mi][ni]);
        }
    }
  }
  const size_t S = (size_t)65536 * 80;   // elements per QKV hi (or lo) array
#pragma unroll
  for (int mi = 0; mi < 2; ++mi)
#pragma unroll
    for (int ni = 0; ni < 2; ++ni)
#pragma unroll
      for (int r = 0; r < 16; ++r) {
        int m = m0 + wm * 64 + mi * 32 + (r & 3) + 8 * (r >> 2) + 4 * hi;
        int c = n0 + wn * 64 + ni * 32 + col;
        int which = c / 1152, cm = c - which * 1152;
        int hh = cm / 72, dd = cm - hh * 72;
        int b = m >> 11, nn = m & 2047;
        size_t idx = (((size_t)(b * 16 + hh)) * 2048 + nn) * 80 + dd;
        float v = acc[mi][ni][r];
        short hb = f2bf(v);
        short* OH = QKV0 + (size_t)which * 2 * S;
        OH[idx] = hb;
        OH[S + idx] = f2bf(v - bf2f(hb));
      }
}

// ------------- softmax denominator PARTIALS via MFMA, q-tile 256, k-half
__global__ __launch_bounds__(256, 2) void k_stats3(
    const short* __restrict__ Qh, const short* __restrict__ Ql,
    const short* __restrict__ Kh, const short* __restrict__ Kl,
    float* __restrict__ ssum)
{
  __shared__ __align__(16) short kh[64 * LSTR];
  __shared__ __align__(16) short kl[64 * LSTR];
  const int tid = threadIdx.x;
  const int wv = tid >> 6, ln = tid & 63;
  const int col = ln & 31, hi = ln >> 5;
  const int hb = blockIdx.x & 31;
  const int rest = blockIdx.x >> 5;
  const int q0 = (rest & 7) * 256;
  const int ks = rest >> 3;               // 0 or 1
  const int h = hb >> 1, b = hb & 1;
  const size_t bhbase = (size_t)(b * H + h) * N * DP;
  const int kbeg = ks * (N / 2), kend = kbeg + N / 2;

  bf16x8 qfh[2][5], qfl[2][5];
#pragma unroll
  for (int mi = 0; mi < 2; ++mi) {
    const size_t rb = bhbase + (size_t)(q0 + wv * 64 + mi * 32 + col) * DP + hi * 8;
#pragma unroll
    for (int d = 0; d < 5; ++d) {
      qfh[mi][d] = *(const bf16x8*)(const void*)(Qh + rb + d * 16);
      qfl[mi][d] = *(const bf16x8*)(const void*)(Ql + rb + d * 16);
    }
  }
  float s[2][16];
#pragma unroll
  for (int mi = 0; mi < 2; ++mi)
#pragma unroll
    for (int r = 0; r < 16; ++r) s[mi][r] = 0.f;

  float4 rkh[3], rkl[3];
  auto LOADK = [&](int kt) {
#pragma unroll
    for (int ss = 0; ss < 3; ++ss) {
      int e = ss * 256 + tid;
      if (e < 640) {
        int r = e / 10, cc = e - r * 10;
        size_t sb = bhbase + (size_t)(kt + r) * DP + cc * 8;
        rkh[ss] = *(const float4*)(const void*)(Kh + sb);
        rkl[ss] = *(const float4*)(const void*)(Kl + sb);
      }
    }
  };
  auto STOREK = [&]() {
#pragma unroll
    for (int ss = 0; ss < 3; ++ss) {
      int e = ss * 256 + tid;
      if (e < 640) {
        int r = e / 10, cc = e - r * 10;
        *(float4*)(void*)(kh + r * LSTR + cc * 8) = rkh[ss];
        *(float4*)(void*)(kl + r * LSTR + cc * 8) = rkl[ss];
      }
    }
  };

  LOADK(kbeg);
  for (int kt = kbeg; kt < kend; kt += 64) {
    __syncthreads();
    STOREK();
    __syncthreads();
    if (kt + 64 < kend) LOADK(kt + 64);
    f32x16 z[2][2];
#pragma unroll
    for (int mi = 0; mi < 2; ++mi)
#pragma unroll
      for (int rn = 0; rn < 2; ++rn)
#pragma unroll
        for (int r = 0; r < 16; ++r) z[mi][rn][r] = 0.f;
#pragma unroll
    for (int d = 0; d < 5; ++d) {
      const int boff = d * 16 + hi * 8;
      bf16x8 bh0 = *(const bf16x8*)(const void*)(kh + col * LSTR + boff);
      bf16x8 bl0 = *(const bf16x8*)(const void*)(kl + col * LSTR + boff);
      bf16x8 bh1 = *(const bf16x8*)(const void*)(kh + (32 + col) * LSTR + boff);
      bf16x8 bl1 = *(const bf16x8*)(const void*)(kl + (32 + col) * LSTR + boff);
#pragma unroll
      for (int mi = 0; mi < 2; ++mi) {
        z[mi][0] = mfma_bf16(qfh[mi][d], bh0, z[mi][0]);
        z[mi][0] = mfma_bf16(qfh[mi][d], bl0, z[mi][0]);
        z[mi][0] = mfma_bf16(qfl[mi][d], bh0, z[mi][0]);
        z[mi][1] = mfma_bf16(qfh[mi][d], bh1, z[mi][1]);
        z[mi][1] = mfma_bf16(qfh[mi][d], bl1, z[mi][1]);
        z[mi][1] = mfma_bf16(qfl[mi][d], bh1, z[mi][1]);
      }
    }
#pragma unroll
    for (int mi = 0; mi < 2; ++mi)
#pragma unroll
      for (int r = 0; r < 16; ++r)
        s[mi][r] += __expf(z[mi][0][r] * SCALE) + __expf(z[mi][1][r] * SCALE);
  }
#pragma unroll
  for (int mi = 0; mi < 2; ++mi)
#pragma unroll
    for (int r = 0; r < 16; ++r) {
      float v = s[mi][r];
#pragma unroll
      for (int o = 1; o < 32; o <<= 1) v += __shfl_xor(v, o);
      if (col == 0) {
        int row = q0 + wv * 64 + mi * 32 + ((r & 3) + ((r >> 2) << 3) + (hi << 2));
        ssum[(size_t)ks * ROWS + (size_t)(b * H + h) * N + row] = v;
      }
    }
}

// --------------- head-averaged attention matrix, q-tile 256 x k-tile 64
// inv computed inline from the 2 ssum halves (k_sinv folded in; same fp order)
__global__ __launch_bounds__(256, 2) void k_attn3(
    const short* __restrict__ Qh, const short* __restrict__ Ql,
    const short* __restrict__ Kh, const short* __restrict__ Kl,
    const float* __restrict__ ssum, float* __restrict__ attn,
    float* __restrict__ part8)
{
  __shared__ __align__(16) short kh[64 * LSTR];
  __shared__ __align__(16) short kl[64 * LSTR];
  __shared__ float invs[256];
  __shared__ float colred[64][8];
  const int tid = threadIdx.x;
  const int wv = tid >> 6, ln = tid & 63;
  const int col = ln & 31, hi = ln >> 5;
  const int q0 = (blockIdx.x & 7) * 256;
  const int b = (blockIdx.x >> 3) & 1;
  const int k0 = (blockIdx.x >> 4) * 64;

  f32x16 pa[2][2];
#pragma unroll
  for (int mi = 0; mi < 2; ++mi)
#pragma unroll
    for (int rn = 0; rn < 2; ++rn)
#pragma unroll
      for (int r = 0; r < 16; ++r) pa[mi][rn][r] = 0.f;

  float4 rkh[3], rkl[3];
  float rin;
  auto LOADH = [&](int h) {
    const size_t hb = (size_t)(b * H + h) * N * DP;
#pragma unroll
    for (int ss = 0; ss < 3; ++ss) {
      int e = ss * 256 + tid;
      if (e < 640) {
        int r = e / 10, cc = e - r * 10;
        size_t sb = hb + (size_t)(k0 + r) * DP + cc * 8;
        rkh[ss] = *(const float4*)(const void*)(Kh + sb);
        rkl[ss] = *(const float4*)(const void*)(Kl + sb);
      }
    }
    size_t si = (size_t)(b * H + h) * N + q0 + tid;
    rin = 1.0f / (ssum[si] + ssum[(size_t)ROWS + si]);
  };
  auto STOREH = [&]() {
#pragma unroll
    for (int ss = 0; ss < 3; ++ss) {
      int e = ss * 256 + tid;
      if (e < 640) {
        int r = e / 10, cc = e - r * 10;
        *(float4*)(void*)(kh + r * LSTR + cc * 8) = rkh[ss];
        *(float4*)(void*)(kl + r * LSTR + cc * 8) = rkl[ss];
      }
    }
    invs[tid] = rin;
  };

  LOADH(0);
  for (int h = 0; h < H; ++h) {
    __syncthreads();
    STOREH();
    __syncthreads();
    if (h + 1 < H) LOADH(h + 1);

    const size_t bhbase = (size_t)(b * H + h) * N * DP;
    f32x16 z[2][2];
#pragma unroll
    for (int mi = 0; mi < 2; ++mi)
#pragma unroll
      for (int rn = 0; rn < 2; ++rn)
#pragma unroll
        for (int r = 0; r < 16; ++r) z[mi][rn][r] = 0.f;

#pragma unroll
    for (int d = 0; d < 5; ++d) {
      const int boff = d * 16 + hi * 8;
      bf16x8 bh0 = *(const bf16x8*)(const void*)(kh + col * LSTR + boff);
      bf16x8 bl0 = *(const bf16x8*)(const void*)(kl + col * LSTR + boff);
      bf16x8 bh1 = *(const bf16x8*)(const void*)(kh + (32 + col) * LSTR + boff);
      bf16x8 bl1 = *(const bf16x8*)(const void*)(kl + (32 + col) * LSTR + boff);
      bf16x8 qh0 = *(const bf16x8*)(const void*)(Qh + bhbase + (size_t)(q0 + wv * 64 + col) * DP + boff);
      bf16x8 ql0 = *(const bf16x8*)(const void*)(Ql + bhbase + (size_t)(q0 + wv * 64 + col) * DP + boff);
      bf16x8 qh1 = *(const bf16x8*)(const void*)(Qh + bhbase + (size_t)(q0 + wv * 64 + 32 + col) * DP + boff);
      bf16x8 ql1 = *(const bf16x8*)(const void*)(Ql + bhbase + (size_t)(q0 + wv * 64 + 32 + col) * DP + boff);
      z[0][0] = mfma_bf16(qh0, bh0, z[0][0]);
      z[0][0] = mfma_bf16(qh0, bl0, z[0][0]);
      z[0][0] = mfma_bf16(ql0, bh0, z[0][0]);
      z[0][1] = mfma_bf16(qh0, bh1, z[0][1]);
      z[0][1] = mfma_bf16(qh0, bl1, z[0][1]);
      z[0][1] = mfma_bf16(ql0, bh1, z[0][1]);
      z[1][0] = mfma_bf16(qh1, bh0, z[1][0]);
      z[1][0] = mfma_bf16(qh1, bl0, z[1][0]);
      z[1][0] = mfma_bf16(ql1, bh0, z[1][0]);
      z[1][1] = mfma_bf16(qh1, bh1, z[1][1]);
      z[1][1] = mfma_bf16(qh1, bl1, z[1][1]);
      z[1][1] = mfma_bf16(ql1, bh1, z[1][1]);
    }
#pragma unroll
    for (int mi = 0; mi < 2; ++mi)
#pragma unroll
      for (int r = 0; r < 16; ++r) {
        const int rloc = wv * 64 + mi * 32 + (r & 3) + ((r >> 2) << 3) + (hi << 2);
        const float iv = invs[rloc];
        pa[mi][0][r] += __expf(z[mi][0][r] * SCALE) * iv;
        pa[mi][1][r] += __expf(z[mi][1][r] * SCALE) * iv;
      }
  }
  const float invH = 1.0f / H;
#pragma unroll
  for (int mi = 0; mi < 2; ++mi)
#pragma unroll
    for (int r = 0; r < 16; ++r) {
      const int row = q0 + wv * 64 + mi * 32 + (r & 3) + ((r >> 2) << 3) + (hi << 2);
      attn[((size_t)b * N + row) * N + k0 + col] = pa[mi][0][r] * invH;
      attn[((size_t)b * N + row) * N + k0 + 32 + col] = pa[mi][1][r] * invH;
    }
  // ---- first matvec partials: per-column sum over this block's 256 rows
  __syncthreads();
#pragma unroll
  for (int rn = 0; rn < 2; ++rn) {
    float s = 0.f;
#pragma unroll
    for (int mi = 0; mi < 2; ++mi)
#pragma unroll
      for (int r = 0; r < 16; ++r) s += pa[mi][rn][r];
    colred[rn * 32 + col][wv * 2 + hi] = s * invH;
  }
  __syncthreads();
  if (tid < 64) {
    float s = 0.f;
#pragma unroll
    for (int u = 0; u < 8; ++u) s += colred[tid][u];
    part8[(size_t)(q0 >> 8) * (B * N) + b * N + k0 + tid] = s * (1.0f / N);
  }
}

// matvec step: reduce nin slices of partial_in for this block's 64 rows, matvec
// 4-way split accumulator breaks the serial FMA dependency chain.
__global__ __launch_bounds__(256) void k_powfused(
    const float* __restrict__ attn, const float* __restrict__ partial_in,
    float* __restrict__ partial_out, int nin)
{
  __shared__ float red[4][64];
  __shared__ float ds[64];
  const int tid = threadIdx.x;
  const int g = blockIdx.x * 256 + tid;
  const int sy = blockIdx.y;
  const int b = g / N, j = g % N;
  const int i0 = sy * ILEN;
  {
    int i = tid & 63, sgrp = tid >> 6;
    const int per = nin >> 2;
    const float* p = partial_in + (size_t)(b * N + i0 + i);
    float s8 = 0.f;
    for (int k = 0; k < per; ++k) s8 += p[(size_t)(sgrp * per + k) * (B * N)];
    red[sgrp][i] = s8;
  }
  __syncthreads();
  if (tid < 64) ds[tid] = red[0][tid] + red[1][tid] + red[2][tid] + red[3][tid];
  __syncthreads();
  const float* ab = attn + (size_t)b * N * N;
  float s0 = 0.f, s1 = 0.f, s2 = 0.f, s3 = 0.f;
  for (int i = 0; i < ILEN; i += 4) {
    s0 += ds[i + 0] * ab[(size_t)(i0 + i + 0) * N + j];
    s1 += ds[i + 1] * ab[(size_t)(i0 + i + 1) * N + j];
    s2 += ds[i + 2] * ab[(size_t)(i0 + i + 2) * N + j];
    s3 += ds[i + 3] * ab[(size_t)(i0 + i + 3) * N + j];
  }
  partial_out[(size_t)sy * (B * N) + g] = (s0 + s1) + (s2 + s3);
}

// ------- top-k partition (bitonic sort); input = 32-slice partial vector
// Also emits prune_list (pruned original indices, any order; writes disjoint).
__global__ __launch_bounds__(1024) void k_partition(
    const float* __restrict__ partial, int* __restrict__ sorted_imp,
    int* __restrict__ keepflag, int* __restrict__ s_map,
    int* __restrict__ prune_list)
{
  __shared__ float v[N];
  __shared__ int   id[N];
  __shared__ int   kf[N];
  __shared__ int   ps[N];
  const int tid = threadIdx.x;
  const int b = blockIdx.x;
  for (int i = tid; i < N; i += 1024) {
    float s = 0.f;
    const float* p = partial + (size_t)(b * N + i);
    for (int sy = 0; sy < PSL; ++sy) s += p[(size_t)sy * (B * N)];
    v[i] = s; id[i] = i;
  }
  for (int k = 2; k <= N; k <<= 1) {
    for (int j = k >> 1; j > 0; j >>= 1) {
      __syncthreads();
      for (int i = tid; i < N; i += 1024) {
        int ixj = i ^ j;
        if (ixj > i) {
          bool up = ((i & k) == 0);
          float va = v[i], vb = v[ixj];
          int ia = id[i], ib = id[ixj];
          bool b_before_a = (vb > va) || (vb == va && ib < ia);
          if (b_before_a == up) { v[i] = vb; v[ixj] = va; id[i] = ib; id[ixj] = ia; }
        }
      }
    }
  }
  __syncthreads();
  for (int i = tid; i < N; i += 1024) {
    kf[id[i]] = (i < NKEEP) ? 1 : 0;
    if (i >= NKEEP) prune_list[b * NPRUNE + (i - NKEEP)] = id[i];
  }
  __syncthreads();
  for (int i = tid; i < N; i += 1024) ps[i] = kf[i];
  for (int off = 1; off < N; off <<= 1) {
    __syncthreads();
    int t0 = (tid >= off) ? ps[tid - off] : 0;
    int i1 = tid + 1024;
    int t1 = ps[i1 - off];
    __syncthreads();
    ps[tid] += t0;
    ps[i1] += t1;
  }
  __syncthreads();
  for (int i = tid; i < N; i += 1024) {
    int excl = ps[i] - kf[i];
    keepflag[b * N + i] = kf[i];
    if (kf[i]) { sorted_imp[b * NKEEP + excl] = i; s_map[b * N + i] = excl; }
  }
}

// --------------- per-column argmax over kept rows, sliced (16x parallelism)
__global__ __launch_bounds__(256) void k_argmax_part(
    const float* __restrict__ attn, const int* __restrict__ sorted_imp,
    float* __restrict__ pval, int* __restrict__ pidx)
{
  __shared__ int imp_s[ACH];
  const int tid = threadIdx.x;
  const int g = blockIdx.x * 256 + tid;
  const int s = blockIdx.y;
  const int b = g / N, n = g % N;
  const int k0 = s * ACH;
  const int k1 = (k0 + ACH < NKEEP) ? k0 + ACH : NKEEP;
  const int cnt = k1 - k0;
  for (int i = tid; i < cnt; i += 256) imp_s[i] = sorted_imp[b * NKEEP + k0 + i];
  __syncthreads();
  const float* ab = attn + (size_t)b * N * N;
  float best = -FINF; int bi = k0;
  for (int k = 0; k < cnt; ++k) {
    float val = ab[(size_t)imp_s[k] * N + n];
    if (val > best) { best = val; bi = k0 + k; }   // strict >: first max
  }
  pval[(size_t)s * (B * N) + g] = best;
  pidx[(size_t)s * (B * N) + g] = bi;
}

// combine ascending: strict > keeps earliest k on ties (jnp.argmax semantics)
__global__ __launch_bounds__(256) void k_argmax_comb(
    const float* __restrict__ pval, const int* __restrict__ pidx,
    const int* __restrict__ keepflag, int* __restrict__ s_map)
{
  int g = blockIdx.x * 256 + threadIdx.x;
  if (g >= B * N) return;
  float best = -FINF; int bi = 0;
#pragma unroll
  for (int s = 0; s < ASL; ++s) {
    float v = pval[(size_t)s * (B * N) + g];
    if (v > best) { best = v; bi = pidx[(size_t)s * (B * N) + g]; }
  }
  if (!keepflag[g]) s_map[g] = bi;
}

// -------- fused reduced attention, KV-SPLIT: gathered QK^T + exp + PV (MFMA)
__global__ __launch_bounds__(256, 2) void k_rfused(
    const short* __restrict__ Qh, const short* __restrict__ Ql,
    const short* __restrict__ Kh, const short* __restrict__ Kl,
    const short* __restrict__ Vh, const int* __restrict__ sorted_imp,
    float* __restrict__ Opart, float* __restrict__ dpart)
{
  constexpr int LK = 88;
  constexpr int VTS = 72;
  __shared__ __align__(16) short KhS[64 * LK];
  __shared__ __align__(16) short KlS[64 * LK];
  __shared__ __align__(16) short VhS[64 * LK];
  __shared__ __align__(16) short VT[72 * VTS];
  __shared__ int imp[NKEEP];
  const int tid = threadIdx.x;
  const int wv = tid >> 6, ln = tid & 63;
  const int col = ln & 31, hi = ln >> 5;
  const int b = blockIdx.z & 1, ks = blockIdx.z >> 1;
  const int h = blockIdx.y, q0 = blockIdx.x * 128;
  const int kbeg = ks ? 448 : 0, kend = ks ? 832 : 448;
  const size_t bh80 = (size_t)(b * H + h) * N * DP;
  for (int i = tid; i < NKEEP; i += 256) imp[i] = sorted_imp[b * NKEEP + i];
  __syncthreads();
  int qr = q0 + wv * 32 + col;
  int qi = imp[qr < NKEEP ? qr : NKEEP - 1];
  bf16x8 qfh[5], qfl[5];
  {
    const size_t qb = bh80 + (size_t)qi * DP + hi * 8;
#pragma unroll
    for (int d = 0; d < 5; ++d) {
      qfh[d] = *(const bf16x8*)(const void*)(Qh + qb + d * 16);
      qfl[d] = *(const bf16x8*)(const void*)(Ql + qb + d * 16);
    }
  }
  float denom = 0.f;
  f32x16 oacc[3];
#pragma unroll
  for (int nc = 0; nc < 3; ++nc)
#pragma unroll
    for (int r = 0; r < 16; ++r) oacc[nc][r] = 0.f;

  for (int kt = kbeg; kt < kend; kt += 64) {
    for (int e = tid; e < 640; e += 256) {
      int r = e / 10, cc = e - r * 10;
      int kv = kt + r;
      float4 vkh, vkl, vvh;
      if (kv < NKEEP) {
        size_t sb = bh80 + (size_t)imp[kv] * DP + cc * 8;
        vkh = *(const float4*)(const void*)(Kh + sb);
        vkl = *(const float4*)(const void*)(Kl + sb);
        vvh = *(const float4*)(const void*)(Vh + sb);
      } else {
        vkh = make_float4(0.f, 0.f, 0.f, 0.f); vkl = vkh; vvh = vkh;
      }
      *(float4*)(void*)&KhS[r * LK + cc * 8] = vkh;
      *(float4*)(void*)&KlS[r * LK + cc * 8] = vkl;
      *(float4*)(void*)&VhS[r * LK + cc * 8] = vvh;
    }
    __syncthreads();
    f32x16 z[2];
#pragma unroll
    for (int rn = 0; rn < 2; ++rn)
#pragma unroll
      for (int r = 0; r < 16; ++r) z[rn][r] = 0.f;
#pragma unroll
    for (int d = 0; d < 5; ++d) {
      const int boff = d * 16 + hi * 8;
#pragma unroll
      for (int rn = 0; rn < 2; ++rn) {
        bf16x8 kfh = *(const bf16x8*)(const void*)(KhS + (rn * 32 + col) * LK + boff);
        bf16x8 kfl = *(const bf16x8*)(const void*)(KlS + (rn * 32 + col) * LK + boff);
        z[rn] = mfma_bf16(kfh, qfh[d], z[rn]);
        z[rn] = mfma_bf16(kfh, qfl[d], z[rn]);
        z[rn] = mfma_bf16(kfl, qfh[d], z[rn]);
      }
    }
    for (int e = tid; e < 576; e += 256) {
      int dd = e % 72, k8 = e / 72;
      short8 t;
#pragma unroll
      for (int j = 0; j < 8; ++j) t[j] = VhS[(k8 * 8 + j) * LK + dd];
      *(short8*)(void*)&VT[dd * VTS + k8 * 8] = t;
    }
    const bool full = (kt + 64 <= NKEEP);
#pragma unroll
    for (int rn = 0; rn < 2; ++rn) {
      int kvb = kt + rn * 32 + 4 * hi;
#pragma unroll
      for (int r = 0; r < 16; ++r) {
        float pe = __expf(z[rn][r] * SCALE);
        if (!full) {
          int kv = kvb + (r & 3) + 8 * (r >> 2);
          pe = (kv < NKEEP) ? pe : 0.f;
        }
        z[rn][r] = pe;
        denom += pe;
      }
    }
    __syncthreads();
#pragma unroll
    for (int rn = 0; rn < 2; ++rn) {
#pragma unroll
      for (int kc = 0; kc < 2; ++kc) {
        unsigned p0, p1, p2, p3;
        asm("v_cvt_pk_bf16_f32 %0, %1, %2" : "=v"(p0) : "v"(z[rn][8 * kc + 0]), "v"(z[rn][8 * kc + 1]));
        asm("v_cvt_pk_bf16_f32 %0, %1, %2" : "=v"(p1) : "v"(z[rn][8 * kc + 2]), "v"(z[rn][8 * kc + 3]));
        asm("v_cvt_pk_bf16_f32 %0, %1, %2" : "=v"(p2) : "v"(z[rn][8 * kc + 4]), "v"(z[rn][8 * kc + 5]));
        asm("v_cvt_pk_bf16_f32 %0, %1, %2" : "=v"(p3) : "v"(z[rn][8 * kc + 6]), "v"(z[rn][8 * kc + 7]));
        unsigned othA = hi ? p0 : p2, othB = hi ? p1 : p3;
        unsigned swA = (unsigned)__shfl_xor((int)othA, 32);
        unsigned swB = (unsigned)__shfl_xor((int)othB, 32);
        union { unsigned u[4]; bf16x8 v; } pf;
        pf.u[0] = hi ? swA : p0; pf.u[1] = hi ? swB : p1;
        pf.u[2] = hi ? p2 : swA; pf.u[3] = hi ? p3 : swB;
        const int kb = rn * 32 + kc * 16 + hi * 8;
#pragma unroll
        for (int nc = 0; nc < 3; ++nc) {
          int dr = nc * 32 + col; if (dr > 71) dr = 71;
          bf16x8 vf = *(const bf16x8*)(const void*)(VT + dr * VTS + kb);
          oacc[nc] = mfma_bf16(pf.v, vf, oacc[nc]);
        }
      }
    }
  }
  // unnormalized O-partial write (no cross-lane needed)
#pragma unroll
  for (int r = 0; r < 16; ++r) {
    int cr = (r & 3) + 8 * (r >> 2) + 4 * hi;
    int q = q0 + wv * 32 + cr;
    if (q < NKEEP) {
#pragma unroll
      for (int nc = 0; nc < 3; ++nc) {
        int dd = nc * 32 + col;
        if (dd < 72)
          Opart[(size_t)ks * OSZ + ((size_t)b * NKEEP + q) * 1152 + h * 72 + dd] =
              oacc[nc][r];
      }
    }
  }
  denom += __shfl_xor(denom, 32);
  if (hi == 0) {
    int q = q0 + wv * 32 + col;
    if (q < NKEEP)
      dpart[ks * DSZ + (b * H + h) * NKEEP + q] = denom;
  }
}

// ---- combine KV-half partials: Y = (O0+O1) * 1/(d0+d1), bf16 hi/lo split
__global__ __launch_bounds__(256) void k_rcomb(
    const float* __restrict__ Opart, const float* __restrict__ dpart,
    short* __restrict__ Yh, short* __restrict__ Yl)
{
  size_t g = (size_t)blockIdx.x * 256 + threadIdx.x;   // grid exact: OSZ/256
  int c = (int)(g % 1152);
  int q = (int)((g / 1152) % NKEEP);
  int b = (int)(g / ((size_t)NKEEP * 1152));
  int h = c / 72;
  float o = Opart[g] + Opart[OSZ + g];
  float d = dpart[(b * H + h) * NKEEP + q] + dpart[DSZ + (b * H + h) * NKEEP + q];
  float v = o * (1.0f / d);
  short hb = f2bf(v);
  Yh[g] = hb;
  Yl[g] = f2bf(v - bf2f(hb));
}

// ---- output projection, SCATTERED epilogue: writes kept rows directly into
// out[b][sorted_imp[m]] (rows are 4.6KB contiguous -> coalescing preserved)
__global__ __launch_bounds__(256, 2) void k_ogemm(
    const short* __restrict__ Ah_g, const short* __restrict__ Al_g,
    const short* __restrict__ Bh_g, const short* __restrict__ Bl_g,
    const int* __restrict__ sorted_imp,
    float* __restrict__ OutF, const float* __restrict__ bias,
    int Mtot)
{
  constexpr int LK = 40;
  __shared__ short AhS[64 * LK], AlS[64 * LK], BhS[64 * LK], BlS[64 * LK];
  const int tid = threadIdx.x;
  const int wv = tid >> 6, ln = tid & 63;
  const int col = ln & 31, hi = ln >> 5;
  const int wm = wv >> 1, wn = wv & 1;
  const int m0 = blockIdx.y * 64, n0 = blockIdx.x * 64;
  f32x16 acc;
#pragma unroll
  for (int r = 0; r < 16; ++r) acc[r] = 0.f;

  for (int kt = 0; kt < 1152; kt += 32) {
    __syncthreads();
    {
      int e = tid;
      int r = e >> 2, c4 = e & 3;
      int ra = m0 + r; if (ra >= Mtot) ra = Mtot - 1;
      size_t sa = (size_t)ra * 1152 + kt + c4 * 8;
      *(float4*)&AhS[r * LK + c4 * 8] = *(const float4*)(Ah_g + sa);
      *(float4*)&AlS[r * LK + c4 * 8] = *(const float4*)(Al_g + sa);
      size_t sb = (size_t)(n0 + r) * 1152 + kt + c4 * 8;
      *(float4*)&BhS[r * LK + c4 * 8] = *(const float4*)(Bh_g + sb);
      *(float4*)&BlS[r * LK + c4 * 8] = *(const float4*)(Bl_g + sb);
    }
    __syncthreads();
#pragma unroll
    for (int kc = 0; kc < 2; ++kc) {
      int ra = wm * 32 + col;
      int rb = wn * 32 + col;
      bf16x8 ah = *(const bf16x8*)&AhS[ra * LK + kc * 16 + hi * 8];
      bf16x8 al = *(const bf16x8*)&AlS[ra * LK + kc * 16 + hi * 8];
      bf16x8 bh = *(const bf16x8*)&BhS[rb * LK + kc * 16 + hi * 8];
      bf16x8 bl = *(const bf16x8*)&BlS[rb * LK + kc * 16 + hi * 8];
      acc = mfma_bf16(ah, bh, acc);
      acc = mfma_bf16(ah, bl, acc);
      acc = mfma_bf16(al, bh, acc);
    }
  }
#pragma unroll
  for (int r = 0; r < 16; ++r) {
    int m = m0 + wm * 32 + (r & 3) + 8 * (r >> 2) + 4 * hi;
    int c = n0 + wn * 32 + col;
    if (m < Mtot) {
      int b = m / NKEEP, mm = m - b * NKEEP;
      int orig = sorted_imp[b * NKEEP + mm];
      OutF[((size_t)b * N + orig) * 1152 + c] = acc[r] + bias[c];
    }
  }
}

// ---- pruned-row copy (compacted): only B*NPRUNE*QD threads
__global__ __launch_bounds__(256) void k_prune(
    const int* __restrict__ prune_list, const int* __restrict__ sorted_imp,
    const int* __restrict__ s_map, float* __restrict__ out)
{
  size_t g = (size_t)blockIdx.x * 256 + threadIdx.x;
  if (g >= (size_t)B * NPRUNE * QD) return;
  int c = (int)(g % QD);
  int j = (int)((g / QD) % NPRUNE);
  int b = (int)(g / ((size_t)NPRUNE * QD));
  int n_ = prune_list[b * NPRUNE + j];
  int src = sorted_imp[b * NKEEP + s_map[b * N + n_]];
  out[((size_t)b * N + n_) * QD + c] = out[((size_t)b * N + src) * QD + c];
}

// ---------------------------------------------------------------- launch
extern "C" void kernel_launch(void* const* d_in, const int* in_sizes, int n_in,
                              void* d_out, int out_size, void* d_ws, size_t ws_size,
                              hipStream_t stream)
{
  const float* x  = (const float*)d_in[0];
  const float* Wq = (const float*)d_in[1];
  const float* Wk = (const float*)d_in[2];
  const float* Wv = (const float*)d_in[3];
  const float* Wo = (const float*)d_in[4];
  const float* bo = (const float*)d_in[5];
  float* out = (float*)d_out;

  char* ws = (char*)d_ws;
  size_t off = 0;
  auto alloc = [&](size_t bytes) -> void* {
    void* p = ws + off;
    off = (off + bytes + 255) & ~(size_t)255;
    return p;
  };
  const size_t XEL = (size_t)B * N * QD;    // 4718592
  const size_t WEL = (size_t)QD * INNER;    // 1327104
  short* xh   = (short*)alloc(sizeof(short) * XEL);
  short* xl   = (short*)alloc(sizeof(short) * XEL);
  short* WTh  = (short*)alloc(sizeof(short) * WEL * 3);   // [Wq|Wk|Wv]^T hi
  short* WTl  = (short*)alloc(sizeof(short) * WEL * 3);   // lo
  short* WoTh = (short*)alloc(sizeof(short) * WEL);
  short* WoTl = (short*)alloc(sizeof(short) * WEL);
  short* Qhb  = (short*)alloc(sizeof(short) * (size_t)ROWS * DP);
  short* Qlb  = (short*)alloc(sizeof(short) * (size_t)ROWS * DP);
  short* Khb  = (short*)alloc(sizeof(short) * (size_t)ROWS * DP);
  short* Klb  = (short*)alloc(sizeof(short) * (size_t)ROWS * DP);
  short* Vhb  = (short*)alloc(sizeof(short) * (size_t)ROWS * DP);
  short* Vlb  = (short*)alloc(sizeof(short) * (size_t)ROWS * DP);
  float* attn = (float*)alloc(sizeof(float) * (size_t)B * N * N);
  float* ssum = (float*)alloc(sizeof(float) * 2 * (size_t)ROWS);
  float* partA = (float*)alloc(sizeof(float) * PSL * B * N);
  float* partB = (float*)alloc(sizeof(float) * PSL * B * N);
  float* dpart = (float*)alloc(sizeof(float) * 2 * DSZ);
  int* sorted_imp = (int*)alloc(sizeof(int) * B * NKEEP);
  int* keepflag   = (int*)alloc(sizeof(int) * B * N);
  int* s_map      = (int*)alloc(sizeof(int) * B * N);
  int* prune_list = (int*)alloc(sizeof(int) * B * NPRUNE);
  float* pval     = (float*)alloc(sizeof(float) * ASL * B * N);
  int*   pidx     = (int*)alloc(sizeof(int) * ASL * B * N);
  (void)Vlb;
  // aliases into dead regions:
  short* Yh = xh;                      // bf16 hi of reduced-attn output
  short* Yl = xh + (size_t)B * NKEEP * INNER;
  float* Opart = attn;                 // 2 x 7.55MB O-partials in dead attn

  dim3 blk(256);

  // prep: vectorized x split + QKV pad zeroing (exact grid), W splits (1 launch)
  k_prep<<<dim3((X4 + 6 * ROWS) / 256), blk, 0, stream>>>(x, xh, xl, Qhb);
  k_wsplit4<<<dim3(QD / 64, QD / 64, 4), blk, 0, stream>>>(
      Wq, Wk, Wv, Wo, WTh, WTl, WoTh, WoTl);

  // fused QKV projection (1D grid 864, XCD-swizzled, direct staging — pinned)
  k_pgemm3<<<dim3(864), blk, 0, stream>>>(xh, xl, WTh, WTl, Qhb);

  // full attention: denominator partials (k-split, 512 blocks) +
  // head-averaged matrix (inv computed inline; + first matvec into partB)
  k_stats3<<<dim3(512), blk, 0, stream>>>(Qhb, Qlb, Khb, Klb, ssum);
  k_attn3<<<dim3(512), blk, 0, stream>>>(Qhb, Qlb, Khb, Klb, ssum, attn, partB);

  // remaining 4 power-iteration matvecs; partition reduces the final 32 slices
  k_powfused<<<dim3(B * N / 256, PSL), blk, 0, stream>>>(attn, partB, partA, 8);
  k_powfused<<<dim3(B * N / 256, PSL), blk, 0, stream>>>(attn, partA, partB, 32);
  k_powfused<<<dim3(B * N / 256, PSL), blk, 0, stream>>>(attn, partB, partA, 32);
  k_powfused<<<dim3(B * N / 256, PSL), blk, 0, stream>>>(attn, partA, partB, 32);

  // top-k partition (+ prune list) + sliced per-column argmax
  k_partition<<<dim3(B), dim3(1024), 0, stream>>>(
      partB, sorted_imp, keepflag, s_map, prune_list);
  k_argmax_part<<<dim3(B * N / 256, ASL), blk, 0, stream>>>(attn, sorted_imp, pval, pidx);
  k_argmax_comb<<<dim3(B * N / 256), blk, 0, stream>>>(pval, pidx, keepflag, s_map);

  // fused reduced attention, KV-split over 448 blocks, then combine
  k_rfused<<<dim3((NKEEP + 127) / 128, H, 2 * B), blk, 0, stream>>>(
      Qhb, Qlb, Khb, Klb, Vhb, sorted_imp, Opart, dpart);
  k_rcomb<<<dim3((int)(OSZ / 256)), blk, 0, stream>>>(Opart, dpart, Yh, Yl);

  // output projection scatter-writes kept rows; compacted prune copies rest
  k_ogemm<<<dim3(QD / 64, (B * NKEEP + 63) / 64), blk, 0, stream>>>(
      Yh, Yl, WoTh, WoTl, sorted_imp, out, bo, B * NKEEP);
  k_prune<<<dim3((int)(((size_t)B * NPRUNE * QD + 255) / 256)), blk, 0, stream>>>(
      prune_list, sorted_imp, s_map, out);
}

// Round 20
// 487.183 us; speedup vs baseline: 1.0330x; 1.0100x over previous
//
#include <hip/hip_runtime.h>

namespace {
constexpr int B = 2;
constexpr int N = 2048;
constexpr int QD = 1152;
constexpr int H = 16;
constexpr int D = 72;
constexpr int INNER = 1152;
constexpr int NKEEP = 819;            // int(2048*0.4)
constexpr int NPRUNE = N - NKEEP;     // 1229
constexpr int PSL = 32;               // power-iteration i-slices (matvec out)
constexpr int ILEN = N / PSL;         // 64
constexpr int DP = 80;                // padded head dim (5 blocks of 16)
constexpr int LSTR = 88;              // LDS row stride (bf16) for DP-wide tiles
constexpr int ASL = 16;               // argmax row-slices
constexpr int ACH = (NKEEP + ASL - 1) / ASL;  // 52
constexpr int ROWS = B * H * N;       // 65536
constexpr int X4 = (B * N * QD) / 4;  // 1179648 float4 units of x
constexpr size_t OSZ = (size_t)B * NKEEP * INNER;  // O-partial stride
constexpr int DSZ = B * H * NKEEP;                 // denom-partial stride
}

#define FINF __builtin_inff()
#define SCALE 0.11785113019775793f

typedef __attribute__((ext_vector_type(8))) __bf16 bf16x8;
typedef __attribute__((ext_vector_type(16))) float f32x16;
typedef __attribute__((ext_vector_type(8))) short short8;
typedef __attribute__((ext_vector_type(4))) short short4v;

__device__ __forceinline__ f32x16 mfma_bf16(bf16x8 a, bf16x8 b, f32x16 c) {
  return __builtin_amdgcn_mfma_f32_32x32x16_bf16(a, b, c, 0, 0, 0);
}
__device__ __forceinline__ short f2bf(float x) {
  unsigned u = __float_as_uint(x);
  unsigned r = (u + 0x7fffu + ((u >> 16) & 1u)) >> 16;
  return (short)r;
}
__device__ __forceinline__ float bf2f(short b) {
  return __uint_as_float(((unsigned)(unsigned short)b) << 16);
}

// ------- prep: vectorized x hi/lo split (float4) + QKV pad-column zeroing
__global__ __launch_bounds__(256) void k_prep(
    const float* __restrict__ X, short* __restrict__ Xh, short* __restrict__ Xl,
    short* __restrict__ qkv)
{
  int g = blockIdx.x * 256 + threadIdx.x;   // grid = X4 + 6*ROWS threads exactly
  if (g < X4) {
    float4 v = ((const float4*)X)[g];
    float vv[4] = {v.x, v.y, v.z, v.w};
    short4v h, l;
#pragma unroll
    for (int i = 0; i < 4; ++i) {
      short hb = f2bf(vv[i]);
      h[i] = hb;
      l[i] = f2bf(vv[i] - bf2f(hb));
    }
    *(short4v*)(void*)(Xh + (size_t)g * 4) = h;
    *(short4v*)(void*)(Xl + (size_t)g * 4) = l;
  } else {
    int t = g - X4;                         // 0 .. 6*ROWS-1
    int arr = t / ROWS, row = t - arr * ROWS;
    *(float4*)(void*)(qkv + (size_t)arr * ROWS * DP + (size_t)row * DP + 72) =
        make_float4(0.f, 0.f, 0.f, 0.f);
  }
}

// ---- W (KxN) -> WT hi/lo (N-major, split); z 0..2 -> Wq/Wk/Wv, z=3 -> Wo
__global__ __launch_bounds__(256) void k_wsplit4(
    const float* __restrict__ W0, const float* __restrict__ W1,
    const float* __restrict__ W2, const float* __restrict__ W3,
    short* __restrict__ WTh, short* __restrict__ WTl,
    short* __restrict__ WoTh, short* __restrict__ WoTl)
{
  __shared__ float tile[64][65];
  const int tid = threadIdx.x;
  const int k0 = blockIdx.y * 64, n0 = blockIdx.x * 64;
  const int z = blockIdx.z;
  const float* W = (z == 0) ? W0 : (z == 1) ? W1 : (z == 2) ? W2 : W3;
  short* outH = (z < 3) ? WTh + (size_t)z * QD * INNER : WoTh;
  short* outL = (z < 3) ? WTl + (size_t)z * QD * INNER : WoTl;
  {
    int r = tid >> 2, c0 = (tid & 3) * 16;
#pragma unroll
    for (int j = 0; j < 16; j += 4) {
      float4 v = *(const float4*)&W[(size_t)(k0 + r) * 1152 + n0 + c0 + j];
      tile[r][c0 + j] = v.x; tile[r][c0 + j + 1] = v.y;
      tile[r][c0 + j + 2] = v.z; tile[r][c0 + j + 3] = v.w;
    }
  }
  __syncthreads();
  for (int e = tid; e < 4096; e += 256) {
    int nr = e >> 6, kc = e & 63;
    float v = tile[kc][nr];
    short hb = f2bf(v);
    outH[(size_t)(n0 + nr) * 1152 + k0 + kc] = hb;
    outL[(size_t)(n0 + nr) * 1152 + k0 + kc] = f2bf(v - bf2f(hb));
  }
}

// ------------ fused QKV projection: A(4096x1152) @ [Wq|Wk|Wv]^T (3456 cols)
// Round-20: T3 "minimum 2-phase" pipeline — DOUBLE-BUFFERED LDS, ONE barrier
// per K-step, stage(kt+32 -> buf^1) issued BEFORE compute(buf). Staging regs
// never cross a barrier (the rounds-5/8 spill mode is structurally absent:
// load->ds_write is a contiguous live range; compute reads the OTHER buffer).
// Spill detector: VGPR<60 + WRITE>300MB -> revert to round-12 single-buffer.
__global__ __launch_bounds__(256, 2) void k_pgemm3(
    const short* __restrict__ Ah_g, const short* __restrict__ Al_g,
    const short* __restrict__ Bh_g, const short* __restrict__ Bl_g,
    short* __restrict__ QKV0)
{
  constexpr int LK = 40;   // 32 k + 8 pad
  __shared__ short AhS[2][128 * LK], AlS[2][128 * LK];
  __shared__ short BhS[2][128 * LK], BlS[2][128 * LK];   // 80 KB total
  const int tid = threadIdx.x;
  const int wv = tid >> 6, ln = tid & 63;
  const int col = ln & 31, hi = ln >> 5;
  const int wm = wv >> 1, wn = wv & 1;
  const int swz = (blockIdx.x & 7) * 108 + (blockIdx.x >> 3);
  const int m0 = (swz / 27) * 128, n0 = (swz % 27) * 128;

  auto STAGE = [&](int bu, int kt) {
#pragma unroll
    for (int e0 = 0; e0 < 2; ++e0) {
      int e = e0 * 256 + tid;
      int r = e >> 2, c4 = e & 3;
      size_t sa = (size_t)(m0 + r) * 1152 + kt + c4 * 8;
      float4 va_h = *(const float4*)(Ah_g + sa);
      float4 va_l = *(const float4*)(Al_g + sa);
      size_t sb = (size_t)(n0 + r) * 1152 + kt + c4 * 8;
      float4 vb_h = *(const float4*)(Bh_g + sb);
      float4 vb_l = *(const float4*)(Bl_g + sb);
      *(float4*)&AhS[bu][r * LK + c4 * 8] = va_h;
      *(float4*)&AlS[bu][r * LK + c4 * 8] = va_l;
      *(float4*)&BhS[bu][r * LK + c4 * 8] = vb_h;
      *(float4*)&BlS[bu][r * LK + c4 * 8] = vb_l;
    }
  };

  f32x16 acc[2][2];
#pragma unroll
  for (int mi = 0; mi < 2; ++mi)
#pragma unroll
    for (int ni = 0; ni < 2; ++ni)
#pragma unroll
      for (int r = 0; r < 16; ++r) acc[mi][ni][r] = 0.f;

  STAGE(0, 0);
  __syncthreads();
  int cur = 0;
  for (int kt = 0; kt < 1152; kt += 32) {
    if (kt + 32 < 1152) STAGE(cur ^ 1, kt + 32);  // overlaps compute below
    const short* AhC = AhS[cur];
    const short* AlC = AlS[cur];
    const short* BhC = BhS[cur];
    const short* BlC = BlS[cur];
#pragma unroll
    for (int kc = 0; kc < 2; ++kc) {
      bf16x8 ah[2], al[2], bh[2], bl[2];
#pragma unroll
      for (int mi = 0; mi < 2; ++mi) {
        int r = wm * 64 + mi * 32 + col;
        ah[mi] = *(const bf16x8*)&AhC[r * LK + kc * 16 + hi * 8];
        al[mi] = *(const bf16x8*)&AlC[r * LK + kc * 16 + hi * 8];
      }
#pragma unroll
      for (int ni = 0; ni < 2; ++ni) {
        int r = wn * 64 + ni * 32 + col;
        bh[ni] = *(const bf16x8*)&BhC[r * LK + kc * 16 + hi * 8];
        bl[ni] = *(const bf16x8*)&BlC[r * LK + kc * 16 + hi * 8];
      }
#pragma unroll
      for (int mi = 0; mi < 2; ++mi)
#pragma unroll
        for (int ni = 0; ni < 2; ++ni) {
          acc[mi][ni] = mfma_bf16(ah[mi], bh[ni], acc[mi][ni]);
          acc[mi][ni] = mfma_bf16(ah[mi], bl[ni], acc[mi][ni]);
          acc[mi][ni] = mfma_bf16(al[mi], bh[ni], acc[mi][ni]);
        }
    }
    __syncthreads();   // writes to buf^1 done before next iter reads it;
    cur ^= 1;          // reads of buf done before iter+2 overwrites it
  }
  const size_t S = (size_t)65536 * 80;   // elements per QKV hi (or lo) array
#pragma unroll
  for (int mi = 0; mi < 2; ++mi)
#pragma unroll
    for (int ni = 0; ni < 2; ++ni)
#pragma unroll
      for (int r = 0; r < 16; ++r) {
        int m = m0 + wm * 64 + mi * 32 + (r & 3) + 8 * (r >> 2) + 4 * hi;
        int c = n0 + wn * 64 + ni * 32 + col;
        int which = c / 1152, cm = c - which * 1152;
        int hh = cm / 72, dd = cm - hh * 72;
        int b = m >> 11, nn = m & 2047;
        size_t idx = (((size_t)(b * 16 + hh)) * 2048 + nn) * 80 + dd;
        float v = acc[mi][ni][r];
        short hb = f2bf(v);
        short* OH = QKV0 + (size_t)which * 2 * S;
        OH[idx] = hb;
        OH[S + idx] = f2bf(v - bf2f(hb));
      }
}

// ------------- softmax denominator PARTIALS via MFMA, q-tile 256, k-half
__global__ __launch_bounds__(256, 2) void k_stats3(
    const short* __restrict__ Qh, const short* __restrict__ Ql,
    const short* __restrict__ Kh, const short* __restrict__ Kl,
    float* __restrict__ ssum)
{
  __shared__ __align__(16) short kh[64 * LSTR];
  __shared__ __align__(16) short kl[64 * LSTR];
  const int tid = threadIdx.x;
  const int wv = tid >> 6, ln = tid & 63;
  const int col = ln & 31, hi = ln >> 5;
  const int hb = blockIdx.x & 31;
  const int rest = blockIdx.x >> 5;
  const int q0 = (rest & 7) * 256;
  const int ks = rest >> 3;               // 0 or 1
  const int h = hb >> 1, b = hb & 1;
  const size_t bhbase = (size_t)(b * H + h) * N * DP;
  const int kbeg = ks * (N / 2), kend = kbeg + N / 2;

  bf16x8 qfh[2][5], qfl[2][5];
#pragma unroll
  for (int mi = 0; mi < 2; ++mi) {
    const size_t rb = bhbase + (size_t)(q0 + wv * 64 + mi * 32 + col) * DP + hi * 8;
#pragma unroll
    for (int d = 0; d < 5; ++d) {
      qfh[mi][d] = *(const bf16x8*)(const void*)(Qh + rb + d * 16);
      qfl[mi][d] = *(const bf16x8*)(const void*)(Ql + rb + d * 16);
    }
  }
  float s[2][16];
#pragma unroll
  for (int mi = 0; mi < 2; ++mi)
#pragma unroll
    for (int r = 0; r < 16; ++r) s[mi][r] = 0.f;

  float4 rkh[3], rkl[3];
  auto LOADK = [&](int kt) {
#pragma unroll
    for (int ss = 0; ss < 3; ++ss) {
      int e = ss * 256 + tid;
      if (e < 640) {
        int r = e / 10, cc = e - r * 10;
        size_t sb = bhbase + (size_t)(kt + r) * DP + cc * 8;
        rkh[ss] = *(const float4*)(const void*)(Kh + sb);
        rkl[ss] = *(const float4*)(const void*)(Kl + sb);
      }
    }
  };
  auto STOREK = [&]() {
#pragma unroll
    for (int ss = 0; ss < 3; ++ss) {
      int e = ss * 256 + tid;
      if (e < 640) {
        int r = e / 10, cc = e - r * 10;
        *(float4*)(void*)(kh + r * LSTR + cc * 8) = rkh[ss];
        *(float4*)(void*)(kl + r * LSTR + cc * 8) = rkl[ss];
      }
    }
  };

  LOADK(kbeg);
  for (int kt = kbeg; kt < kend; kt += 64) {
    __syncthreads();
    STOREK();
    __syncthreads();
    if (kt + 64 < kend) LOADK(kt + 64);
    f32x16 z[2][2];
#pragma unroll
    for (int mi = 0; mi < 2; ++mi)
#pragma unroll
      for (int rn = 0; rn < 2; ++rn)
#pragma unroll
        for (int r = 0; r < 16; ++r) z[mi][rn][r] = 0.f;
#pragma unroll
    for (int d = 0; d < 5; ++d) {
      const int boff = d * 16 + hi * 8;
      bf16x8 bh0 = *(const bf16x8*)(const void*)(kh + col * LSTR + boff);
      bf16x8 bl0 = *(const bf16x8*)(const void*)(kl + col * LSTR + boff);
      bf16x8 bh1 = *(const bf16x8*)(const void*)(kh + (32 + col) * LSTR + boff);
      bf16x8 bl1 = *(const bf16x8*)(const void*)(kl + (32 + col) * LSTR + boff);
#pragma unroll
      for (int mi = 0; mi < 2; ++mi) {
        z[mi][0] = mfma_bf16(qfh[mi][d], bh0, z[mi][0]);
        z[mi][0] = mfma_bf16(qfh[mi][d], bl0, z[mi][0]);
        z[mi][0] = mfma_bf16(qfl[mi][d], bh0, z[mi][0]);
        z[mi][1] = mfma_bf16(qfh[mi][d], bh1, z[mi][1]);
        z[mi][1] = mfma_bf16(qfh[mi][d], bl1, z[mi][1]);
        z[mi][1] = mfma_bf16(qfl[mi][d], bh1, z[mi][1]);
      }
    }
#pragma unroll
    for (int mi = 0; mi < 2; ++mi)
#pragma unroll
      for (int r = 0; r < 16; ++r)
        s[mi][r] += __expf(z[mi][0][r] * SCALE) + __expf(z[mi][1][r] * SCALE);
  }
#pragma unroll
  for (int mi = 0; mi < 2; ++mi)
#pragma unroll
    for (int r = 0; r < 16; ++r) {
      float v = s[mi][r];
#pragma unroll
      for (int o = 1; o < 32; o <<= 1) v += __shfl_xor(v, o);
      if (col == 0) {
        int row = q0 + wv * 64 + mi * 32 + ((r & 3) + ((r >> 2) << 3) + (hi << 2));
        ssum[(size_t)ks * ROWS + (size_t)(b * H + h) * N + row] = v;
      }
    }
}

// --------------- head-averaged attention matrix, q-tile 256 x k-tile 64
// inv computed inline from the 2 ssum halves (k_sinv folded in; same fp order)
__global__ __launch_bounds__(256, 2) void k_attn3(
    const short* __restrict__ Qh, const short* __restrict__ Ql,
    const short* __restrict__ Kh, const short* __restrict__ Kl,
    const float* __restrict__ ssum, float* __restrict__ attn,
    float* __restrict__ part8)
{
  __shared__ __align__(16) short kh[64 * LSTR];
  __shared__ __align__(16) short kl[64 * LSTR];
  __shared__ float invs[256];
  __shared__ float colred[64][8];
  const int tid = threadIdx.x;
  const int wv = tid >> 6, ln = tid & 63;
  const int col = ln & 31, hi = ln >> 5;
  const int q0 = (blockIdx.x & 7) * 256;
  const int b = (blockIdx.x >> 3) & 1;
  const int k0 = (blockIdx.x >> 4) * 64;

  f32x16 pa[2][2];
#pragma unroll
  for (int mi = 0; mi < 2; ++mi)
#pragma unroll
    for (int rn = 0; rn < 2; ++rn)
#pragma unroll
      for (int r = 0; r < 16; ++r) pa[mi][rn][r] = 0.f;

  float4 rkh[3], rkl[3];
  float rin;
  auto LOADH = [&](int h) {
    const size_t hb = (size_t)(b * H + h) * N * DP;
#pragma unroll
    for (int ss = 0; ss < 3; ++ss) {
      int e = ss * 256 + tid;
      if (e < 640) {
        int r = e / 10, cc = e - r * 10;
        size_t sb = hb + (size_t)(k0 + r) * DP + cc * 8;
        rkh[ss] = *(const float4*)(const void*)(Kh + sb);
        rkl[ss] = *(const float4*)(const void*)(Kl + sb);
      }
    }
    size_t si = (size_t)(b * H + h) * N + q0 + tid;
    rin = 1.0f / (ssum[si] + ssum[(size_t)ROWS + si]);
  };
  auto STOREH = [&]() {
#pragma unroll
    for (int ss = 0; ss < 3; ++ss) {
      int e = ss * 256 + tid;
      if (e < 640) {
        int r = e / 10, cc = e - r * 10;
        *(float4*)(void*)(kh + r * LSTR + cc * 8) = rkh[ss];
        *(float4*)(void*)(kl + r * LSTR + cc * 8) = rkl[ss];
      }
    }
    invs[tid] = rin;
  };

  LOADH(0);
  for (int h = 0; h < H; ++h) {
    __syncthreads();
    STOREH();
    __syncthreads();
    if (h + 1 < H) LOADH(h + 1);

    const size_t bhbase = (size_t)(b * H + h) * N * DP;
    f32x16 z[2][2];
#pragma unroll
    for (int mi = 0; mi < 2; ++mi)
#pragma unroll
      for (int rn = 0; rn < 2; ++rn)
#pragma unroll
        for (int r = 0; r < 16; ++r) z[mi][rn][r] = 0.f;

#pragma unroll
    for (int d = 0; d < 5; ++d) {
      const int boff = d * 16 + hi * 8;
      bf16x8 bh0 = *(const bf16x8*)(const void*)(kh + col * LSTR + boff);
      bf16x8 bl0 = *(const bf16x8*)(const void*)(kl + col * LSTR + boff);
      bf16x8 bh1 = *(const bf16x8*)(const void*)(kh + (32 + col) * LSTR + boff);
      bf16x8 bl1 = *(const bf16x8*)(const void*)(kl + (32 + col) * LSTR + boff);
      bf16x8 qh0 = *(const bf16x8*)(const void*)(Qh + bhbase + (size_t)(q0 + wv * 64 + col) * DP + boff);
      bf16x8 ql0 = *(const bf16x8*)(const void*)(Ql + bhbase + (size_t)(q0 + wv * 64 + col) * DP + boff);
      bf16x8 qh1 = *(const bf16x8*)(const void*)(Qh + bhbase + (size_t)(q0 + wv * 64 + 32 + col) * DP + boff);
      bf16x8 ql1 = *(const bf16x8*)(const void*)(Ql + bhbase + (size_t)(q0 + wv * 64 + 32 + col) * DP + boff);
      z[0][0] = mfma_bf16(qh0, bh0, z[0][0]);
      z[0][0] = mfma_bf16(qh0, bl0, z[0][0]);
      z[0][0] = mfma_bf16(ql0, bh0, z[0][0]);
      z[0][1] = mfma_bf16(qh0, bh1, z[0][1]);
      z[0][1] = mfma_bf16(qh0, bl1, z[0][1]);
      z[0][1] = mfma_bf16(ql0, bh1, z[0][1]);
      z[1][0] = mfma_bf16(qh1, bh0, z[1][0]);
      z[1][0] = mfma_bf16(qh1, bl0, z[1][0]);
      z[1][0] = mfma_bf16(ql1, bh0, z[1][0]);
      z[1][1] = mfma_bf16(qh1, bh1, z[1][1]);
      z[1][1] = mfma_bf16(qh1, bl1, z[1][1]);
      z[1][1] = mfma_bf16(ql1, bh1, z[1][1]);
    }
#pragma unroll
    for (int mi = 0; mi < 2; ++mi)
#pragma unroll
      for (int r = 0; r < 16; ++r) {
        const int rloc = wv * 64 + mi * 32 + (r & 3) + ((r >> 2) << 3) + (hi << 2);
        const float iv = invs[rloc];
        pa[mi][0][r] += __expf(z[mi][0][r] * SCALE) * iv;
        pa[mi][1][r] += __expf(z[mi][1][r] * SCALE) * iv;
      }
  }
  const float invH = 1.0f / H;
#pragma unroll
  for (int mi = 0; mi < 2; ++mi)
#pragma unroll
    for (int r = 0; r < 16; ++r) {
      const int row = q0 + wv * 64 + mi * 32 + (r & 3) + ((r >> 2) << 3) + (hi << 2);
      attn[((size_t)b * N + row) * N + k0 + col] = pa[mi][0][r] * invH;
      attn[((size_t)b * N + row) * N + k0 + 32 + col] = pa[mi][1][r] * invH;
    }
  // ---- first matvec partials: per-column sum over this block's 256 rows
  __syncthreads();
#pragma unroll
  for (int rn = 0; rn < 2; ++rn) {
    float s = 0.f;
#pragma unroll
    for (int mi = 0; mi < 2; ++mi)
#pragma unroll
      for (int r = 0; r < 16; ++r) s += pa[mi][rn][r];
    colred[rn * 32 + col][wv * 2 + hi] = s * invH;
  }
  __syncthreads();
  if (tid < 64) {
    float s = 0.f;
#pragma unroll
    for (int u = 0; u < 8; ++u) s += colred[tid][u];
    part8[(size_t)(q0 >> 8) * (B * N) + b * N + k0 + tid] = s * (1.0f / N);
  }
}

// matvec step: reduce nin slices of partial_in for this block's 64 rows, matvec
// 4-way split accumulator breaks the serial FMA dependency chain.
__global__ __launch_bounds__(256) void k_powfused(
    const float* __restrict__ attn, const float* __restrict__ partial_in,
    float* __restrict__ partial_out, int nin)
{
  __shared__ float red[4][64];
  __shared__ float ds[64];
  const int tid = threadIdx.x;
  const int g = blockIdx.x * 256 + tid;
  const int sy = blockIdx.y;
  const int b = g / N, j = g % N;
  const int i0 = sy * ILEN;
  {
    int i = tid & 63, sgrp = tid >> 6;
    const int per = nin >> 2;
    const float* p = partial_in + (size_t)(b * N + i0 + i);
    float s8 = 0.f;
    for (int k = 0; k < per; ++k) s8 += p[(size_t)(sgrp * per + k) * (B * N)];
    red[sgrp][i] = s8;
  }
  __syncthreads();
  if (tid < 64) ds[tid] = red[0][tid] + red[1][tid] + red[2][tid] + red[3][tid];
  __syncthreads();
  const float* ab = attn + (size_t)b * N * N;
  float s0 = 0.f, s1 = 0.f, s2 = 0.f, s3 = 0.f;
  for (int i = 0; i < ILEN; i += 4) {
    s0 += ds[i + 0] * ab[(size_t)(i0 + i + 0) * N + j];
    s1 += ds[i + 1] * ab[(size_t)(i0 + i + 1) * N + j];
    s2 += ds[i + 2] * ab[(size_t)(i0 + i + 2) * N + j];
    s3 += ds[i + 3] * ab[(size_t)(i0 + i + 3) * N + j];
  }
  partial_out[(size_t)sy * (B * N) + g] = (s0 + s1) + (s2 + s3);
}

// ------- top-k partition (bitonic sort); input = 32-slice partial vector
// Also emits prune_list (pruned original indices, any order; writes disjoint).
__global__ __launch_bounds__(1024) void k_partition(
    const float* __restrict__ partial, int* __restrict__ sorted_imp,
    int* __restrict__ keepflag, int* __restrict__ s_map,
    int* __restrict__ prune_list)
{
  __shared__ float v[N];
  __shared__ int   id[N];
  __shared__ int   kf[N];
  __shared__ int   ps[N];
  const int tid = threadIdx.x;
  const int b = blockIdx.x;
  for (int i = tid; i < N; i += 1024) {
    float s = 0.f;
    const float* p = partial + (size_t)(b * N + i);
    for (int sy = 0; sy < PSL; ++sy) s += p[(size_t)sy * (B * N)];
    v[i] = s; id[i] = i;
  }
  for (int k = 2; k <= N; k <<= 1) {
    for (int j = k >> 1; j > 0; j >>= 1) {
      __syncthreads();
      for (int i = tid; i < N; i += 1024) {
        int ixj = i ^ j;
        if (ixj > i) {
          bool up = ((i & k) == 0);
          float va = v[i], vb = v[ixj];
          int ia = id[i], ib = id[ixj];
          bool b_before_a = (vb > va) || (vb == va && ib < ia);
          if (b_before_a == up) { v[i] = vb; v[ixj] = va; id[i] = ib; id[ixj] = ia; }
        }
      }
    }
  }
  __syncthreads();
  for (int i = tid; i < N; i += 1024) {
    kf[id[i]] = (i < NKEEP) ? 1 : 0;
    if (i >= NKEEP) prune_list[b * NPRUNE + (i - NKEEP)] = id[i];
  }
  __syncthreads();
  for (int i = tid; i < N; i += 1024) ps[i] = kf[i];
  for (int off = 1; off < N; off <<= 1) {
    __syncthreads();
    int t0 = (tid >= off) ? ps[tid - off] : 0;
    int i1 = tid + 1024;
    int t1 = ps[i1 - off];
    __syncthreads();
    ps[tid] += t0;
    ps[i1] += t1;
  }
  __syncthreads();
  for (int i = tid; i < N; i += 1024) {
    int excl = ps[i] - kf[i];
    keepflag[b * N + i] = kf[i];
    if (kf[i]) { sorted_imp[b * NKEEP + excl] = i; s_map[b * N + i] = excl; }
  }
}

// --------------- per-column argmax over kept rows, sliced (16x parallelism)
__global__ __launch_bounds__(256) void k_argmax_part(
    const float* __restrict__ attn, const int* __restrict__ sorted_imp,
    float* __restrict__ pval, int* __restrict__ pidx)
{
  __shared__ int imp_s[ACH];
  const int tid = threadIdx.x;
  const int g = blockIdx.x * 256 + tid;
  const int s = blockIdx.y;
  const int b = g / N, n = g % N;
  const int k0 = s * ACH;
  const int k1 = (k0 + ACH < NKEEP) ? k0 + ACH : NKEEP;
  const int cnt = k1 - k0;
  for (int i = tid; i < cnt; i += 256) imp_s[i] = sorted_imp[b * NKEEP + k0 + i];
  __syncthreads();
  const float* ab = attn + (size_t)b * N * N;
  float best = -FINF; int bi = k0;
  for (int k = 0; k < cnt; ++k) {
    float val = ab[(size_t)imp_s[k] * N + n];
    if (val > best) { best = val; bi = k0 + k; }   // strict >: first max
  }
  pval[(size_t)s * (B * N) + g] = best;
  pidx[(size_t)s * (B * N) + g] = bi;
}

// combine ascending: strict > keeps earliest k on ties (jnp.argmax semantics)
__global__ __launch_bounds__(256) void k_argmax_comb(
    const float* __restrict__ pval, const int* __restrict__ pidx,
    const int* __restrict__ keepflag, int* __restrict__ s_map)
{
  int g = blockIdx.x * 256 + threadIdx.x;
  if (g >= B * N) return;
  float best = -FINF; int bi = 0;
#pragma unroll
  for (int s = 0; s < ASL; ++s) {
    float v = pval[(size_t)s * (B * N) + g];
    if (v > best) { best = v; bi = pidx[(size_t)s * (B * N) + g]; }
  }
  if (!keepflag[g]) s_map[g] = bi;
}

// -------- fused reduced attention, KV-SPLIT: gathered QK^T + exp + PV (MFMA)
__global__ __launch_bounds__(256, 2) void k_rfused(
    const short* __restrict__ Qh, const short* __restrict__ Ql,
    const short* __restrict__ Kh, const short* __restrict__ Kl,
    const short* __restrict__ Vh, const int* __restrict__ sorted_imp,
    float* __restrict__ Opart, float* __restrict__ dpart)
{
  constexpr int LK = 88;
  constexpr int VTS = 72;
  __shared__ __align__(16) short KhS[64 * LK];
  __shared__ __align__(16) short KlS[64 * LK];
  __shared__ __align__(16) short VhS[64 * LK];
  __shared__ __align__(16) short VT[72 * VTS];
  __shared__ int imp[NKEEP];
  const int tid = threadIdx.x;
  const int wv = tid >> 6, ln = tid & 63;
  const int col = ln & 31, hi = ln >> 5;
  const int b = blockIdx.z & 1, ks = blockIdx.z >> 1;
  const int h = blockIdx.y, q0 = blockIdx.x * 128;
  const int kbeg = ks ? 448 : 0, kend = ks ? 832 : 448;
  const size_t bh80 = (size_t)(b * H + h) * N * DP;
  for (int i = tid; i < NKEEP; i += 256) imp[i] = sorted_imp[b * NKEEP + i];
  __syncthreads();
  int qr = q0 + wv * 32 + col;
  int qi = imp[qr < NKEEP ? qr : NKEEP - 1];
  bf16x8 qfh[5], qfl[5];
  {
    const size_t qb = bh80 + (size_t)qi * DP + hi * 8;
#pragma unroll
    for (int d = 0; d < 5; ++d) {
      qfh[d] = *(const bf16x8*)(const void*)(Qh + qb + d * 16);
      qfl[d] = *(const bf16x8*)(const void*)(Ql + qb + d * 16);
    }
  }
  float denom = 0.f;
  f32x16 oacc[3];
#pragma unroll
  for (int nc = 0; nc < 3; ++nc)
#pragma unroll
    for (int r = 0; r < 16; ++r) oacc[nc][r] = 0.f;

  for (int kt = kbeg; kt < kend; kt += 64) {
    for (int e = tid; e < 640; e += 256) {
      int r = e / 10, cc = e - r * 10;
      int kv = kt + r;
      float4 vkh, vkl, vvh;
      if (kv < NKEEP) {
        size_t sb = bh80 + (size_t)imp[kv] * DP + cc * 8;
        vkh = *(const float4*)(const void*)(Kh + sb);
        vkl = *(const float4*)(const void*)(Kl + sb);
        vvh = *(const float4*)(const void*)(Vh + sb);
      } else {
        vkh = make_float4(0.f, 0.f, 0.f, 0.f); vkl = vkh; vvh = vkh;
      }
      *(float4*)(void*)&KhS[r * LK + cc * 8] = vkh;
      *(float4*)(void*)&KlS[r * LK + cc * 8] = vkl;
      *(float4*)(void*)&VhS[r * LK + cc * 8] = vvh;
    }
    __syncthreads();
    f32x16 z[2];
#pragma unroll
    for (int rn = 0; rn < 2; ++rn)
#pragma unroll
      for (int r = 0; r < 16; ++r) z[rn][r] = 0.f;
#pragma unroll
    for (int d = 0; d < 5; ++d) {
      const int boff = d * 16 + hi * 8;
#pragma unroll
      for (int rn = 0; rn < 2; ++rn) {
        bf16x8 kfh = *(const bf16x8*)(const void*)(KhS + (rn * 32 + col) * LK + boff);
        bf16x8 kfl = *(const bf16x8*)(const void*)(KlS + (rn * 32 + col) * LK + boff);
        z[rn] = mfma_bf16(kfh, qfh[d], z[rn]);
        z[rn] = mfma_bf16(kfh, qfl[d], z[rn]);
        z[rn] = mfma_bf16(kfl, qfh[d], z[rn]);
      }
    }
    for (int e = tid; e < 576; e += 256) {
      int dd = e % 72, k8 = e / 72;
      short8 t;
#pragma unroll
      for (int j = 0; j < 8; ++j) t[j] = VhS[(k8 * 8 + j) * LK + dd];
      *(short8*)(void*)&VT[dd * VTS + k8 * 8] = t;
    }
    const bool full = (kt + 64 <= NKEEP);
#pragma unroll
    for (int rn = 0; rn < 2; ++rn) {
      int kvb = kt + rn * 32 + 4 * hi;
#pragma unroll
      for (int r = 0; r < 16; ++r) {
        float pe = __expf(z[rn][r] * SCALE);
        if (!full) {
          int kv = kvb + (r & 3) + 8 * (r >> 2);
          pe = (kv < NKEEP) ? pe : 0.f;
        }
        z[rn][r] = pe;
        denom += pe;
      }
    }
    __syncthreads();
#pragma unroll
    for (int rn = 0; rn < 2; ++rn) {
#pragma unroll
      for (int kc = 0; kc < 2; ++kc) {
        unsigned p0, p1, p2, p3;
        asm("v_cvt_pk_bf16_f32 %0, %1, %2" : "=v"(p0) : "v"(z[rn][8 * kc + 0]), "v"(z[rn][8 * kc + 1]));
        asm("v_cvt_pk_bf16_f32 %0, %1, %2" : "=v"(p1) : "v"(z[rn][8 * kc + 2]), "v"(z[rn][8 * kc + 3]));
        asm("v_cvt_pk_bf16_f32 %0, %1, %2" : "=v"(p2) : "v"(z[rn][8 * kc + 4]), "v"(z[rn][8 * kc + 5]));
        asm("v_cvt_pk_bf16_f32 %0, %1, %2" : "=v"(p3) : "v"(z[rn][8 * kc + 6]), "v"(z[rn][8 * kc + 7]));
        unsigned othA = hi ? p0 : p2, othB = hi ? p1 : p3;
        unsigned swA = (unsigned)__shfl_xor((int)othA, 32);
        unsigned swB = (unsigned)__shfl_xor((int)othB, 32);
        union { unsigned u[4]; bf16x8 v; } pf;
        pf.u[0] = hi ? swA : p0; pf.u[1] = hi ? swB : p1;
        pf.u[2] = hi ? p2 : swA; pf.u[3] = hi ? p3 : swB;
        const int kb = rn * 32 + kc * 16 + hi * 8;
#pragma unroll
        for (int nc = 0; nc < 3; ++nc) {
          int dr = nc * 32 + col; if (dr > 71) dr = 71;
          bf16x8 vf = *(const bf16x8*)(const void*)(VT + dr * VTS + kb);
          oacc[nc] = mfma_bf16(pf.v, vf, oacc[nc]);
        }
      }
    }
  }
  // unnormalized O-partial write (no cross-lane needed)
#pragma unroll
  for (int r = 0; r < 16; ++r) {
    int cr = (r & 3) + 8 * (r >> 2) + 4 * hi;
    int q = q0 + wv * 32 + cr;
    if (q < NKEEP) {
#pragma unroll
      for (int nc = 0; nc < 3; ++nc) {
        int dd = nc * 32 + col;
        if (dd < 72)
          Opart[(size_t)ks * OSZ + ((size_t)b * NKEEP + q) * 1152 + h * 72 + dd] =
              oacc[nc][r];
      }
    }
  }
  denom += __shfl_xor(denom, 32);
  if (hi == 0) {
    int q = q0 + wv * 32 + col;
    if (q < NKEEP)
      dpart[ks * DSZ + (b * H + h) * NKEEP + q] = denom;
  }
}

// ---- combine KV-half partials: Y = (O0+O1) * 1/(d0+d1), bf16 hi/lo split
__global__ __launch_bounds__(256) void k_rcomb(
    const float* __restrict__ Opart, const float* __restrict__ dpart,
    short* __restrict__ Yh, short* __restrict__ Yl)
{
  size_t g = (size_t)blockIdx.x * 256 + threadIdx.x;   // grid exact: OSZ/256
  int c = (int)(g % 1152);
  int q = (int)((g / 1152) % NKEEP);
  int b = (int)(g / ((size_t)NKEEP * 1152));
  int h = c / 72;
  float o = Opart[g] + Opart[OSZ + g];
  float d = dpart[(b * H + h) * NKEEP + q] + dpart[DSZ + (b * H + h) * NKEEP + q];
  float v = o * (1.0f / d);
  short hb = f2bf(v);
  Yh[g] = hb;
  Yl[g] = f2bf(v - bf2f(hb));
}

// ---- output projection, SCATTERED epilogue: writes kept rows directly into
// out[b][sorted_imp[m]] (rows are 4.6KB contiguous -> coalescing preserved)
__global__ __launch_bounds__(256, 2) void k_ogemm(
    const short* __restrict__ Ah_g, const short* __restrict__ Al_g,
    const short* __restrict__ Bh_g, const short* __restrict__ Bl_g,
    const int* __restrict__ sorted_imp,
    float* __restrict__ OutF, const float* __restrict__ bias,
    int Mtot)
{
  constexpr int LK = 40;
  __shared__ short AhS[64 * LK], AlS[64 * LK], BhS[64 * LK], BlS[64 * LK];
  const int tid = threadIdx.x;
  const int wv = tid >> 6, ln = tid & 63;
  const int col = ln & 31, hi = ln >> 5;
  const int wm = wv >> 1, wn = wv & 1;
  const int m0 = blockIdx.y * 64, n0 = blockIdx.x * 64;
  f32x16 acc;
#pragma unroll
  for (int r = 0; r < 16; ++r) acc[r] = 0.f;

  for (int kt = 0; kt < 1152; kt += 32) {
    __syncthreads();
    {
      int e = tid;
      int r = e >> 2, c4 = e & 3;
      int ra = m0 + r; if (ra >= Mtot) ra = Mtot - 1;
      size_t sa = (size_t)ra * 1152 + kt + c4 * 8;
      *(float4*)&AhS[r * LK + c4 * 8] = *(const float4*)(Ah_g + sa);
      *(float4*)&AlS[r * LK + c4 * 8] = *(const float4*)(Al_g + sa);
      size_t sb = (size_t)(n0 + r) * 1152 + kt + c4 * 8;
      *(float4*)&BhS[r * LK + c4 * 8] = *(const float4*)(Bh_g + sb);
      *(float4*)&BlS[r * LK + c4 * 8] = *(const float4*)(Bl_g + sb);
    }
    __syncthreads();
#pragma unroll
    for (int kc = 0; kc < 2; ++kc) {
      int ra = wm * 32 + col;
      int rb = wn * 32 + col;
      bf16x8 ah = *(const bf16x8*)&AhS[ra * LK + kc * 16 + hi * 8];
      bf16x8 al = *(const bf16x8*)&AlS[ra * LK + kc * 16 + hi * 8];
      bf16x8 bh = *(const bf16x8*)&BhS[rb * LK + kc * 16 + hi * 8];
      bf16x8 bl = *(const bf16x8*)&BlS[rb * LK + kc * 16 + hi * 8];
      acc = mfma_bf16(ah, bh, acc);
      acc = mfma_bf16(ah, bl, acc);
      acc = mfma_bf16(al, bh, acc);
    }
  }
#pragma unroll
  for (int r = 0; r < 16; ++r) {
    int m = m0 + wm * 32 + (r & 3) + 8 * (r >> 2) + 4 * hi;
    int c = n0 + wn * 32 + col;
    if (m < Mtot) {
      int b = m / NKEEP, mm = m - b * NKEEP;
      int orig = sorted_imp[b * NKEEP + mm];
      OutF[((size_t)b * N + orig) * 1152 + c] = acc[r] + bias[c];
    }
  }
}

// ---- pruned-row copy (compacted): only B*NPRUNE*QD threads
__global__ __launch_bounds__(256) void k_prune(
    const int* __restrict__ prune_list, const int* __restrict__ sorted_imp,
    const int* __restrict__ s_map, float* __restrict__ out)
{
  size_t g = (size_t)blockIdx.x * 256 + threadIdx.x;
  if (g >= (size_t)B * NPRUNE * QD) return;
  int c = (int)(g % QD);
  int j = (int)((g / QD) % NPRUNE);
  int b = (int)(g / ((size_t)NPRUNE * QD));
  int n_ = prune_list[b * NPRUNE + j];
  int src = sorted_imp[b * NKEEP + s_map[b * N + n_]];
  out[((size_t)b * N + n_) * QD + c] = out[((size_t)b * N + src) * QD + c];
}

// ---------------------------------------------------------------- launch
extern "C" void kernel_launch(void* const* d_in, const int* in_sizes, int n_in,
                              void* d_out, int out_size, void* d_ws, size_t ws_size,
                              hipStream_t stream)
{
  const float* x  = (const float*)d_in[0];
  const float* Wq = (const float*)d_in[1];
  const float* Wk = (const float*)d_in[2];
  const float* Wv = (const float*)d_in[3];
  const float* Wo = (const float*)d_in[4];
  const float* bo = (const float*)d_in[5];
  float* out = (float*)d_out;

  char* ws = (char*)d_ws;
  size_t off = 0;
  auto alloc = [&](size_t bytes) -> void* {
    void* p = ws + off;
    off = (off + bytes + 255) & ~(size_t)255;
    return p;
  };
  const size_t XEL = (size_t)B * N * QD;    // 4718592
  const size_t WEL = (size_t)QD * INNER;    // 1327104
  short* xh   = (short*)alloc(sizeof(short) * XEL);
  short* xl   = (short*)alloc(sizeof(short) * XEL);
  short* WTh  = (short*)alloc(sizeof(short) * WEL * 3);   // [Wq|Wk|Wv]^T hi
  short* WTl  = (short*)alloc(sizeof(short) * WEL * 3);   // lo
  short* WoTh = (short*)alloc(sizeof(short) * WEL);
  short* WoTl = (short*)alloc(sizeof(short) * WEL);
  short* Qhb  = (short*)alloc(sizeof(short) * (size_t)ROWS * DP);
  short* Qlb  = (short*)alloc(sizeof(short) * (size_t)ROWS * DP);
  short* Khb  = (short*)alloc(sizeof(short) * (size_t)ROWS * DP);
  short* Klb  = (short*)alloc(sizeof(short) * (size_t)ROWS * DP);
  short* Vhb  = (short*)alloc(sizeof(short) * (size_t)ROWS * DP);
  short* Vlb  = (short*)alloc(sizeof(short) * (size_t)ROWS * DP);
  float* attn = (float*)alloc(sizeof(float) * (size_t)B * N * N);
  float* ssum = (float*)alloc(sizeof(float) * 2 * (size_t)ROWS);
  float* partA = (float*)alloc(sizeof(float) * PSL * B * N);
  float* partB = (float*)alloc(sizeof(float) * PSL * B * N);
  float* dpart = (float*)alloc(sizeof(float) * 2 * DSZ);
  int* sorted_imp = (int*)alloc(sizeof(int) * B * NKEEP);
  int* keepflag   = (int*)alloc(sizeof(int) * B * N);
  int* s_map      = (int*)alloc(sizeof(int) * B * N);
  int* prune_list = (int*)alloc(sizeof(int) * B * NPRUNE);
  float* pval     = (float*)alloc(sizeof(float) * ASL * B * N);
  int*   pidx     = (int*)alloc(sizeof(int) * ASL * B * N);
  (void)Vlb;
  // aliases into dead regions:
  short* Yh = xh;                      // bf16 hi of reduced-attn output
  short* Yl = xh + (size_t)B * NKEEP * INNER;
  float* Opart = attn;                 // 2 x 7.55MB O-partials in dead attn

  dim3 blk(256);

  // prep: vectorized x split + QKV pad zeroing (exact grid), W splits (1 launch)
  k_prep<<<dim3((X4 + 6 * ROWS) / 256), blk, 0, stream>>>(x, xh, xl, Qhb);
  k_wsplit4<<<dim3(QD / 64, QD / 64, 4), blk, 0, stream>>>(
      Wq, Wk, Wv, Wo, WTh, WTl, WoTh, WoTl);

  // fused QKV projection (1D grid 864, XCD-swizzled, 2-phase dbuf pipeline)
  k_pgemm3<<<dim3(864), blk, 0, stream>>>(xh, xl, WTh, WTl, Qhb);

  // full attention: denominator partials (k-split, 512 blocks) +
  // head-averaged matrix (inv computed inline; + first matvec into partB)
  k_stats3<<<dim3(512), blk, 0, stream>>>(Qhb, Qlb, Khb, Klb, ssum);
  k_attn3<<<dim3(512), blk, 0, stream>>>(Qhb, Qlb, Khb, Klb, ssum, attn, partB);

  // remaining 4 power-iteration matvecs; partition reduces the final 32 slices
  k_powfused<<<dim3(B * N / 256, PSL), blk, 0, stream>>>(attn, partB, partA, 8);
  k_powfused<<<dim3(B * N / 256, PSL), blk, 0, stream>>>(attn, partA, partB, 32);
  k_powfused<<<dim3(B * N / 256, PSL), blk, 0, stream>>>(attn, partB, partA, 32);
  k_powfused<<<dim3(B * N / 256, PSL), blk, 0, stream>>>(attn, partA, partB, 32);

  // top-k partition (+ prune list) + sliced per-column argmax
  k_partition<<<dim3(B), dim3(1024), 0, stream>>>(
      partB, sorted_imp, keepflag, s_map, prune_list);
  k_argmax_part<<<dim3(B * N / 256, ASL), blk, 0, stream>>>(attn, sorted_imp, pval, pidx);
  k_argmax_comb<<<dim3(B * N / 256), blk, 0, stream>>>(pval, pidx, keepflag, s_map);

  // fused reduced attention, KV-split over 448 blocks, then combine
  k_rfused<<<dim3((NKEEP + 127) / 128, H, 2 * B), blk, 0, stream>>>(
      Qhb, Qlb, Khb, Klb, Vhb, sorted_imp, Opart, dpart);
  k_rcomb<<<dim3((int)(OSZ / 256)), blk, 0, stream>>>(Opart, dpart, Yh, Yl);

  // output projection scatter-writes kept rows; compacted prune copies rest
  k_ogemm<<<dim3(QD / 64, (B * NKEEP + 63) / 64), blk, 0, stream>>>(
      Yh, Yl, WoTh, WoTl, sorted_imp, out, bo, B * NKEEP);
  k_prune<<<dim3((int)(((size_t)B * NPRUNE * QD + 255) / 256)), blk, 0, stream>>>(
      prune_list, sorted_imp, s_map, out);
}